// Round 2
// baseline (2098.802 us; speedup 1.0000x reference)
//
#include <hip/hip_runtime.h>
#include <math.h>

#define NQ 10
#define DIM 1024
#define NLAYERS 6
#define BATCH 16384

// ws layout (floats): [0,480) gate matrices u[l][w][8] (re/im pairs of u00,u01,u10,u11)
//                     [512,1536) wsum[i] = sum_k fc_w[k] * (1 - 2*bit_k(i))
#define WS_WSUM_OFF 512

__global__ __launch_bounds__(1024) void prep_kernel(const float* __restrict__ qw,
                                                    const float* __restrict__ fcw,
                                                    float* __restrict__ ws) {
    const int t = threadIdx.x;  // 1024 threads, 1 block
    if (t < NLAYERS * NQ) {
        float phi = qw[t * 3 + 0];
        float th  = qw[t * 3 + 1];
        float om  = qw[t * 3 + 2];
        float s, c;
        sincosf(0.5f * th, &s, &c);
        float sa, ca, sb, cb;
        sincosf(0.5f * (phi + om), &sa, &ca);
        sincosf(0.5f * (phi - om), &sb, &cb);
        float* u = ws + t * 8;
        // u00 = e^{-i(phi+om)/2} c ; u01 = -e^{+i(phi-om)/2} s
        // u10 = e^{-i(phi-om)/2} s ; u11 = e^{+i(phi+om)/2} c
        u[0] =  ca * c;  u[1] = -sa * c;
        u[2] = -cb * s;  u[3] = -sb * s;
        u[4] =  cb * s;  u[5] = -sb * s;
        u[6] =  ca * c;  u[7] =  sa * c;
    }
    // per-state sign-weight
    float wsum = 0.f;
#pragma unroll
    for (int k = 0; k < NQ; ++k) {
        int bit = (t >> (NQ - 1 - k)) & 1;
        wsum += fcw[k] * (float)(1 - 2 * bit);
    }
    ws[WS_WSUM_OFF + t] = wsum;
}

__device__ __forceinline__ float2 cmadd2(float2 u, float2 a, float2 v, float2 b) {
    // u*a + v*b (complex)
    float re = u.x * a.x - u.y * a.y + v.x * b.x - v.y * b.y;
    float im = u.x * a.y + u.y * a.x + v.x * b.y + v.y * b.x;
    return make_float2(re, im);
}

__device__ __forceinline__ float2 shfl_xor2(float2 a, int mask) {
    return make_float2(__shfl_xor(a.x, mask, 64), __shfl_xor(a.y, mask, 64));
}

__global__ __launch_bounds__(256) void qsim_kernel(const float* __restrict__ x,
                                                   const float* __restrict__ ws,
                                                   const float* __restrict__ fcb,
                                                   float* __restrict__ out) {
    const int lane = threadIdx.x & 63;
    const int wid  = threadIdx.x >> 6;
    const int b    = blockIdx.x * 4 + wid;

    // angles for this batch row (wave-uniform loads)
    float cq[NQ], sq[NQ];
#pragma unroll
    for (int q = 0; q < NQ; ++q) {
        float h = 0.5f * x[b * NQ + q];
        __sincosf(h, &sq[q], &cq[q]);
    }

    // initial product state: amplitude(i) = (prod bit? s:c) * (-i)^popc(i)
    // layout: state index i = (v<<6) | lane, v = register index
    float2 st[16];
#pragma unroll
    for (int v = 0; v < 16; ++v) {
        const int i = (v << 6) | lane;
        float mag = 1.f;
#pragma unroll
        for (int q = 0; q < NQ; ++q) {
            int bit = (i >> (NQ - 1 - q)) & 1;
            mag *= bit ? sq[q] : cq[q];
        }
        const int k = __popc(i) & 3;
        float re = (k == 0) ? mag : ((k == 2) ? -mag : 0.f);
        float im = (k == 1) ? -mag : ((k == 3) ? mag : 0.f);
        st[v] = make_float2(re, im);
    }

#pragma unroll
    for (int l = 0; l < NLAYERS; ++l) {
        // ---- single-qubit rotations ----
#pragma unroll
        for (int w = 0; w < NQ; ++w) {
            const float* u = ws + (l * NQ + w) * 8;
            const float2 u00 = make_float2(u[0], u[1]);
            const float2 u01 = make_float2(u[2], u[3]);
            const float2 u10 = make_float2(u[4], u[5]);
            const float2 u11 = make_float2(u[6], u[7]);
            const int p = NQ - 1 - w;  // bit position of qubit w
            if (p >= 6) {
                // pair lives across register indices
                const int vs = 1 << (p - 6);
#pragma unroll
                for (int v = 0; v < 16; ++v) {
                    if (v & vs) continue;
                    float2 a  = st[v];
                    float2 bb = st[v | vs];
                    st[v]      = cmadd2(u00, a, u01, bb);
                    st[v | vs] = cmadd2(u10, a, u11, bb);
                }
            } else {
                // pair lives across lanes
                const int m = 1 << p;
                const bool hi = (lane & m) != 0;
                const float2 ca = hi ? u11 : u00;  // coeff on my own value
                const float2 cb = hi ? u10 : u01;  // coeff on partner value
#pragma unroll
                for (int v = 0; v < 16; ++v) {
                    float2 mine = st[v];
                    float2 oth  = shfl_xor2(mine, m);
                    st[v] = cmadd2(ca, mine, cb, oth);
                }
            }
        }
        // ---- CNOT ring: control w, target (w+r)%NQ ----
        const int r = l % (NQ - 1) + 1;
#pragma unroll
        for (int w = 0; w < NQ; ++w) {
            const int c  = w;
            const int tq = (w + r) % NQ;
            const int pc = NQ - 1 - c;
            const int pt = NQ - 1 - tq;
            if (pc >= 6 && pt >= 6) {
                // both in register bits: compile-time swap
                const int cm = 1 << (pc - 6), tm = 1 << (pt - 6);
#pragma unroll
                for (int v = 0; v < 16; ++v) {
                    if ((v & cm) && !(v & tm)) {
                        float2 tmp = st[v];
                        st[v] = st[v | tm];
                        st[v | tm] = tmp;
                    }
                }
            } else if (pc >= 6) {
                // control in register bits, target in lane bits
                const int cm = 1 << (pc - 6), tm = 1 << pt;
#pragma unroll
                for (int v = 0; v < 16; ++v) {
                    if (v & cm) st[v] = shfl_xor2(st[v], tm);
                }
            } else if (pt >= 6) {
                // control in lane bits, target in register bits
                const int cm = 1 << pc, tm = 1 << (pt - 6);
                const bool ctl = (lane & cm) != 0;
#pragma unroll
                for (int v = 0; v < 16; ++v) {
                    if (v & tm) continue;
                    float2 a  = st[v];
                    float2 bb = st[v | tm];
                    st[v]      = ctl ? bb : a;
                    st[v | tm] = ctl ? a  : bb;
                }
            } else {
                // both in lane bits
                const int cm = 1 << pc, tm = 1 << pt;
                const bool ctl = (lane & cm) != 0;
#pragma unroll
                for (int v = 0; v < 16; ++v) {
                    float2 o = shfl_xor2(st[v], tm);
                    st[v] = ctl ? o : st[v];
                }
            }
        }
    }

    // ---- expectation: out[b] = fc_b + sum_i |st_i|^2 * wsum[i] ----
    const float* wsum = ws + WS_WSUM_OFF;
    float acc = 0.f;
#pragma unroll
    for (int v = 0; v < 16; ++v) {
        float p = st[v].x * st[v].x + st[v].y * st[v].y;
        acc = fmaf(p, wsum[(v << 6) | lane], acc);
    }
#pragma unroll
    for (int off = 32; off > 0; off >>= 1) acc += __shfl_down(acc, off, 64);
    if (lane == 0) out[b] = acc + fcb[0];
}

extern "C" void kernel_launch(void* const* d_in, const int* in_sizes, int n_in,
                              void* d_out, int out_size, void* d_ws, size_t ws_size,
                              hipStream_t stream) {
    const float* x    = (const float*)d_in[0];
    const float* qw   = (const float*)d_in[1];
    const float* fcw  = (const float*)d_in[2];
    const float* fcb  = (const float*)d_in[3];
    float* out = (float*)d_out;
    float* ws  = (float*)d_ws;

    prep_kernel<<<1, 1024, 0, stream>>>(qw, fcw, ws);
    qsim_kernel<<<BATCH / 4, 256, 0, stream>>>(x, ws, fcb, out);
}

// Round 5
// 426.188 us; speedup vs baseline: 4.9246x; 4.9246x over previous
//
#include <hip/hip_runtime.h>
#include <math.h>

#define NQ 10
#define DIM 1024
#define NLAYERS 6
#define BATCH 16384

// ws layout (floats): [0,480) gate matrices u[l][w][8] (re/im pairs of u00,u01,u10,u11)
//                     [512,1536) wsum[i] = sum_k fc_w[k] * (1 - 2*bit_k(i))
#define WS_WSUM_OFF 512

__global__ __launch_bounds__(1024) void prep_kernel(const float* __restrict__ qw,
                                                    const float* __restrict__ fcw,
                                                    float* __restrict__ ws) {
    const int t = threadIdx.x;  // 1024 threads, 1 block
    if (t < NLAYERS * NQ) {
        float phi = qw[t * 3 + 0];
        float th  = qw[t * 3 + 1];
        float om  = qw[t * 3 + 2];
        float s, c;
        sincosf(0.5f * th, &s, &c);
        float sa, ca, sb, cb;
        sincosf(0.5f * (phi + om), &sa, &ca);
        sincosf(0.5f * (phi - om), &sb, &cb);
        float* u = ws + t * 8;
        // u00 = e^{-i(phi+om)/2} c ; u01 = -e^{+i(phi-om)/2} s
        // u10 = e^{-i(phi-om)/2} s ; u11 = e^{+i(phi+om)/2} c
        u[0] =  ca * c;  u[1] = -sa * c;
        u[2] = -cb * s;  u[3] = -sb * s;
        u[4] =  cb * s;  u[5] = -sb * s;
        u[6] =  ca * c;  u[7] =  sa * c;
    }
    // per-state sign-weight
    float wsum = 0.f;
#pragma unroll
    for (int k = 0; k < NQ; ++k) {
        int bit = (t >> (NQ - 1 - k)) & 1;
        wsum += fcw[k] * (float)(1 - 2 * bit);
    }
    ws[WS_WSUM_OFF + t] = wsum;
}

__device__ __forceinline__ float2 cmadd2(float2 u, float2 a, float2 v, float2 b) {
    // u*a + v*b (complex)
    float re = u.x * a.x - u.y * a.y + v.x * b.x - v.y * b.y;
    float im = u.x * a.y + u.y * a.x + v.x * b.y + v.y * b.x;
    return make_float2(re, im);
}

__device__ __forceinline__ float2 shfl_xor2(float2 a, int mask) {
    return make_float2(__shfl_xor(a.x, mask, 64), __shfl_xor(a.y, mask, 64));
}

// CNOT ring for shift R: control w, target (w+R)%NQ, for w = 0..NQ-1.
// All st[] indices are compile-time constants (R is a template param, w is
// fully unrolled) -> SROA keeps st in VGPRs.
template<int R>
__device__ __forceinline__ void cnot_ring(float2 st[16], int lane) {
#pragma unroll
    for (int w = 0; w < NQ; ++w) {
        const int tq = (w + R) % NQ;
        const int pc = NQ - 1 - w;
        const int pt = NQ - 1 - tq;
        if (pc >= 6 && pt >= 6) {
            const int cm = 1 << (pc - 6), tm = 1 << (pt - 6);
#pragma unroll
            for (int v = 0; v < 16; ++v) {
                if ((v & cm) && !(v & tm)) {
                    float2 tmp = st[v];
                    st[v] = st[v | tm];
                    st[v | tm] = tmp;
                }
            }
        } else if (pc >= 6) {
            const int cm = 1 << (pc - 6), tm = 1 << pt;
#pragma unroll
            for (int v = 0; v < 16; ++v) {
                if (v & cm) st[v] = shfl_xor2(st[v], tm);
            }
        } else if (pt >= 6) {
            const int cm = 1 << pc, tm = 1 << (pt - 6);
            const bool ctl = (lane & cm) != 0;
#pragma unroll
            for (int v = 0; v < 16; ++v) {
                if (v & tm) continue;
                float2 a  = st[v];
                float2 bb = st[v | tm];
                st[v]      = ctl ? bb : a;
                st[v | tm] = ctl ? a  : bb;
            }
        } else {
            const int cm = 1 << pc, tm = 1 << pt;
            const bool ctl = (lane & cm) != 0;
#pragma unroll
            for (int v = 0; v < 16; ++v) {
                float2 o = shfl_xor2(st[v], tm);
                st[v] = ctl ? o : st[v];
            }
        }
    }
}

__global__ __launch_bounds__(256) void qsim_kernel(const float* __restrict__ x,
                                                   const float* __restrict__ ws,
                                                   const float* __restrict__ fcb,
                                                   float* __restrict__ out) {
    const int lane = threadIdx.x & 63;
    const int wid  = threadIdx.x >> 6;
    const int b    = blockIdx.x * 4 + wid;

    // angles for this batch row (wave-uniform loads)
    float cq[NQ], sq[NQ];
#pragma unroll
    for (int q = 0; q < NQ; ++q) {
        float ss, cc;
        __sincosf(0.5f * x[b * NQ + q], &ss, &cc);
        sq[q] = ss; cq[q] = cc;
    }

    // initial product state: amplitude(i) = (prod bit? s:c) * (-i)^popc(i)
    // layout: state index i = (v<<6) | lane, v = register index
    float2 st[16];
#pragma unroll
    for (int v = 0; v < 16; ++v) {
        const int i = (v << 6) | lane;
        float mag = 1.f;
#pragma unroll
        for (int q = 0; q < NQ; ++q) {
            int bit = (i >> (NQ - 1 - q)) & 1;
            mag *= bit ? sq[q] : cq[q];
        }
        const int k = __popc(i) & 3;
        float re = (k == 0) ? mag : ((k == 2) ? -mag : 0.f);
        float im = (k == 1) ? -mag : ((k == 3) ? mag : 0.f);
        st[v] = make_float2(re, im);
    }

    // layer loop kept ROLLED: code stays small (I-cache), all st[] indexing
    // inside is still compile-time static.
#pragma unroll 1
    for (int l = 0; l < NLAYERS; ++l) {
        // ---- single-qubit rotations (w unrolled; l only affects the uniform
        //      coefficient address -> scalar loads) ----
#pragma unroll
        for (int w = 0; w < NQ; ++w) {
            const float* u = ws + (l * NQ + w) * 8;
            const float2 u00 = make_float2(u[0], u[1]);
            const float2 u01 = make_float2(u[2], u[3]);
            const float2 u10 = make_float2(u[4], u[5]);
            const float2 u11 = make_float2(u[6], u[7]);
            const int p = NQ - 1 - w;  // bit position of qubit w
            if (p >= 6) {
                const int vs = 1 << (p - 6);
#pragma unroll
                for (int v = 0; v < 16; ++v) {
                    if (v & vs) continue;
                    float2 a  = st[v];
                    float2 bb = st[v | vs];
                    st[v]      = cmadd2(u00, a, u01, bb);
                    st[v | vs] = cmadd2(u10, a, u11, bb);
                }
            } else {
                const int m = 1 << p;
                const bool hi = (lane & m) != 0;
                const float2 ca = hi ? u11 : u00;  // coeff on my own value
                const float2 cb = hi ? u10 : u01;  // coeff on partner value
#pragma unroll
                for (int v = 0; v < 16; ++v) {
                    float2 mine = st[v];
                    float2 oth  = shfl_xor2(mine, m);
                    st[v] = cmadd2(ca, mine, cb, oth);
                }
            }
        }
        // ---- CNOT ring: r = l % (NQ-1) + 1; static body per layer ----
        switch (l) {
            case 0: cnot_ring<1>(st, lane); break;
            case 1: cnot_ring<2>(st, lane); break;
            case 2: cnot_ring<3>(st, lane); break;
            case 3: cnot_ring<4>(st, lane); break;
            case 4: cnot_ring<5>(st, lane); break;
            default: cnot_ring<6>(st, lane); break;
        }
    }

    // ---- expectation: out[b] = fc_b + sum_i |st_i|^2 * wsum[i] ----
    const float* wsum = ws + WS_WSUM_OFF;
    float acc = 0.f;
#pragma unroll
    for (int v = 0; v < 16; ++v) {
        float p = st[v].x * st[v].x + st[v].y * st[v].y;
        acc = fmaf(p, wsum[(v << 6) | lane], acc);
    }
#pragma unroll
    for (int off = 32; off > 0; off >>= 1) acc += __shfl_down(acc, off, 64);
    if (lane == 0) out[b] = acc + fcb[0];
}

extern "C" void kernel_launch(void* const* d_in, const int* in_sizes, int n_in,
                              void* d_out, int out_size, void* d_ws, size_t ws_size,
                              hipStream_t stream) {
    const float* x    = (const float*)d_in[0];
    const float* qw   = (const float*)d_in[1];
    const float* fcw  = (const float*)d_in[2];
    const float* fcb  = (const float*)d_in[3];
    float* out = (float*)d_out;
    float* ws  = (float*)d_ws;

    prep_kernel<<<1, 1024, 0, stream>>>(qw, fcw, ws);
    qsim_kernel<<<BATCH / 4, 256, 0, stream>>>(x, ws, fcb, out);
}

// Round 6
// 337.207 us; speedup vs baseline: 6.2241x; 1.2639x over previous
//
#include <hip/hip_runtime.h>
#include <math.h>

#define NQ 10
#define DIM 1024
#define NLAYERS 6
#define BATCH 16384

// ============================================================================
// Compile-time GF(2) linear algebra.
// CNOT(c,t): psi'[i] = psi[L i], L = I + E_{pt,pc} (bit positions p = 9-qubit).
// A ring of CNOTs composes to K; we never apply it -- we relabel:
//   stored[j] = logical[T j],  T_{l+1} = K_l^{-1} T_l,  Tinv_{l+1} = Tinv_l K_l.
// Gate on qubit q at layer l acts on stored pairs j, j^m with
//   m = column_{9-q}(Tinv_l), role(j) = parity(row_{9-q}(T_l) & j).
// ============================================================================
struct F2Mat { unsigned short row[NQ]; };

constexpr F2Mat f2_id() {
    F2Mat m{}; for (int i = 0; i < NQ; ++i) m.row[i] = (unsigned short)(1u << i);
    return m;
}
constexpr F2Mat f2_mul(F2Mat A, F2Mat B) {  // (A*B).row[i] = XOR_{j in A.row[i]} B.row[j]
    F2Mat C{};
    for (int i = 0; i < NQ; ++i) {
        unsigned r = 0;
        for (int j = 0; j < NQ; ++j) if ((A.row[i] >> j) & 1u) r ^= B.row[j];
        C.row[i] = (unsigned short)r;
    }
    return C;
}
constexpr bool f2_is_id(F2Mat A) {
    for (int i = 0; i < NQ; ++i) if (A.row[i] != (1u << i)) return false;
    return true;
}
constexpr F2Mat L_mat(int pc, int pt) {  // CNOT index-map matrix
    F2Mat m = f2_id();
    m.row[pt] = (unsigned short)((1u << pt) | (1u << pc));
    return m;
}
// Ring l applies CNOT(w, (w+r)%NQ) for w=0..9 in order; psi_after[i]=psi[K i],
// K = L_{w0} * L_{w1} * ... * L_{w9}.
constexpr F2Mat ring_K(int l) {
    int r = l % (NQ - 1) + 1;
    F2Mat K = f2_id();
    for (int w = 0; w < NQ; ++w) K = f2_mul(K, L_mat(NQ - 1 - w, NQ - 1 - (w + r) % NQ));
    return K;
}
constexpr F2Mat ring_Kinv(int l) {  // each L self-inverse -> reverse product
    int r = l % (NQ - 1) + 1;
    F2Mat K = f2_id();
    for (int w = NQ - 1; w >= 0; --w) K = f2_mul(K, L_mat(NQ - 1 - w, NQ - 1 - (w + r) % NQ));
    return K;
}
struct Tables { F2Mat T[NLAYERS + 1]; F2Mat Tinv[NLAYERS]; };
constexpr Tables make_tables() {
    Tables t{};
    t.T[0] = f2_id();
    F2Mat tinv = f2_id();
    for (int l = 0; l < NLAYERS; ++l) {
        t.Tinv[l] = tinv;
        t.T[l + 1] = f2_mul(ring_Kinv(l), t.T[l]);
        tinv = f2_mul(tinv, ring_K(l));
    }
    return t;
}
static constexpr Tables TB = make_tables();
static_assert(f2_is_id(f2_mul(ring_K(0), ring_Kinv(0))), "ring inverse");
static_assert(f2_is_id(f2_mul(TB.T[1], TB.Tinv[1])), "T1*Tinv1");
static_assert(f2_is_id(f2_mul(TB.T[3], TB.Tinv[3])), "T3*Tinv3");
static_assert(f2_is_id(f2_mul(TB.T[5], TB.Tinv[5])), "T5*Tinv5");
constexpr unsigned f2_col(F2Mat M, int p) {
    unsigned m = 0;
    for (int i = 0; i < NQ; ++i) m |= (((unsigned)M.row[i] >> p) & 1u) << i;
    return m;
}
// Runtime-indexed copy for the prep kernel.
__constant__ Tables dTB = make_tables();

// ws layout (floats):
//   [0,120)          {cos(th/2), sin(th/2)} per (l,q)
//   [128, 12416)     6 diagonals, each float2[1024]  (head + 5 boundaries)
//   [12416, 13440)   W_stored[j] = sum_k fc[k]*(1-2*bit_{9-k}(T6 j))
#define WS_CS   0
#define WS_DIAG 128
#define WS_W    12416

// Rot(phi,th,om) = D1 * Y * D2 with Y=[[c,-s],[s,c]],
// D2=diag(e^{-i phi/2}, e^{i phi/2}), D1=diag(e^{-i om/2}, e^{i om/2}).
// Head diagonal = Dpre_0 (T0=I). Boundary l (0..4):
//   G_l[j] = Dpost_l[T_l j] * Dpre_{l+1}[T_{l+1} j]
// Trailing Dpost_5 is pure phase (killed by |.|^2); Ring_5 folds into W via T6.
__global__ __launch_bounds__(1024) void prep_kernel(const float* __restrict__ qw,
                                                    const float* __restrict__ fcw,
                                                    float* __restrict__ ws) {
    const int j = threadIdx.x;  // 1024 threads, 1 block
    if (j < NLAYERS * NQ) {
        float s, c;
        sincosf(0.5f * qw[3 * j + 1], &s, &c);
        ws[WS_CS + 2 * j]     = c;
        ws[WS_CS + 2 * j + 1] = s;
    }
    // readout weights with final relabeling baked in
    float w = 0.f;
#pragma unroll
    for (int k = 0; k < NQ; ++k) {
        int b = __popc(j & (int)dTB.T[NLAYERS].row[NQ - 1 - k]) & 1;
        w += fcw[k] * (float)(1 - 2 * b);
    }
    ws[WS_W + j] = w;

    float2* D = (float2*)(ws + WS_DIAG);
    {   // head: Dpre_0 at T0 = I
        float ang = 0.f;
#pragma unroll
        for (int q = 0; q < NQ; ++q) {
            int b = (j >> (NQ - 1 - q)) & 1;
            ang += qw[3 * q + 0] * (float)(1 - 2 * b);
        }
        float sn, cn;
        sincosf(-0.5f * ang, &sn, &cn);
        D[j] = make_float2(cn, sn);
    }
#pragma unroll
    for (int l = 0; l < NLAYERS - 1; ++l) {
        float ang = 0.f;
#pragma unroll
        for (int q = 0; q < NQ; ++q) {
            int b1 = __popc(j & (int)dTB.T[l].row[NQ - 1 - q]) & 1;       // omega_l
            ang += qw[3 * (l * NQ + q) + 2] * (float)(1 - 2 * b1);
            int b2 = __popc(j & (int)dTB.T[l + 1].row[NQ - 1 - q]) & 1;   // phi_{l+1}
            ang += qw[3 * ((l + 1) * NQ + q) + 0] * (float)(1 - 2 * b2);
        }
        float sn, cn;
        sincosf(-0.5f * ang, &sn, &cn);
        D[(l + 1) * DIM + j] = make_float2(cn, sn);
    }
}

__device__ __forceinline__ float2 shfl_xor2(float2 a, int mask) {
    return make_float2(__shfl_xor(a.x, mask, 64), __shfl_xor(a.y, mask, 64));
}

// One real Givens rotation on generalized qubit (L,Q). 4 VALU/amplitude.
template<int L, int Q>
__device__ __forceinline__ void apply_gate(float2 st[16], int lane,
                                           const float* __restrict__ ws) {
    constexpr unsigned m     = f2_col(TB.Tinv[L], NQ - 1 - Q);
    constexpr unsigned mreg  = m >> 6;
    constexpr unsigned mlane = m & 63u;
    constexpr unsigned f     = TB.T[L].row[NQ - 1 - Q];
    constexpr unsigned flane = f & 63u;
    constexpr unsigned freg  = f >> 6;
    const float c = ws[WS_CS + 2 * (L * NQ + Q)];
    const float s = ws[WS_CS + 2 * (L * NQ + Q) + 1];
    // coeff on partner: role 0 -> -s, role 1 -> +s; role = cpar(v) ^ parity(lane&flane)
    float cs0;
    if constexpr (flane != 0) {
        int lp = __popc(lane & (int)flane) & 1;
        cs0 = lp ? s : -s;
    } else {
        cs0 = -s;
    }
    const float cs1 = -cs0;
    float2 olds[16];
#pragma unroll
    for (int v = 0; v < 16; ++v) olds[v] = st[v];
#pragma unroll
    for (int v = 0; v < 16; ++v) {
        float2 oth;
        if constexpr (mlane != 0) oth = shfl_xor2(olds[v ^ (int)mreg], (int)mlane);
        else                      oth = olds[v ^ (int)mreg];
        const float co = (__popc((int)(freg & (unsigned)v)) & 1) ? cs1 : cs0;
        st[v] = make_float2(fmaf(co, oth.x, c * olds[v].x),
                            fmaf(co, oth.y, c * olds[v].y));
    }
}

template<int L>
__device__ __forceinline__ void apply_layer(float2 st[16], int lane,
                                            const float* __restrict__ ws) {
    apply_gate<L, 0>(st, lane, ws); apply_gate<L, 1>(st, lane, ws);
    apply_gate<L, 2>(st, lane, ws); apply_gate<L, 3>(st, lane, ws);
    apply_gate<L, 4>(st, lane, ws); apply_gate<L, 5>(st, lane, ws);
    apply_gate<L, 6>(st, lane, ws); apply_gate<L, 7>(st, lane, ws);
    apply_gate<L, 8>(st, lane, ws); apply_gate<L, 9>(st, lane, ws);
}

__device__ __forceinline__ void apply_diag(float2 st[16], const float2* __restrict__ g,
                                           int lane) {
#pragma unroll
    for (int v = 0; v < 16; ++v) {
        float2 G = g[(v << 6) | lane];   // coalesced, L1/L2-resident
        float2 a = st[v];
        st[v] = make_float2(fmaf(a.x, G.x, -(a.y * G.y)),
                            fmaf(a.x, G.y,   a.y * G.x));
    }
}

__global__ __launch_bounds__(256) void qsim_kernel(const float* __restrict__ x,
                                                   const float* __restrict__ ws,
                                                   const float* __restrict__ fcb,
                                                   float* __restrict__ out) {
    const int lane = threadIdx.x & 63;
    const int wid  = threadIdx.x >> 6;
    const int b    = blockIdx.x * 4 + wid;

    float cq[NQ], sq[NQ];
#pragma unroll
    for (int q = 0; q < NQ; ++q) {
        float ss, cc;
        __sincosf(0.5f * x[b * NQ + q], &ss, &cc);
        sq[q] = ss; cq[q] = cc;
    }

    // initial product state: amp(i) = (prod bit? s:c) * (-i)^popc(i); i=(v<<6)|lane
    float2 st[16];
#pragma unroll
    for (int v = 0; v < 16; ++v) {
        const int i = (v << 6) | lane;
        float mag = 1.f;
#pragma unroll
        for (int q = 0; q < NQ; ++q) {
            int bit = (i >> (NQ - 1 - q)) & 1;
            mag *= bit ? sq[q] : cq[q];
        }
        const int k = __popc(i) & 3;
        float re = (k == 0) ? mag : ((k == 2) ? -mag : 0.f);
        float im = (k == 1) ? -mag : ((k == 3) ? mag : 0.f);
        st[v] = make_float2(re, im);
    }

    const float2* D = (const float2*)(ws + WS_DIAG);
    apply_diag(st, D, lane);                                        // Dpre_0
    apply_layer<0>(st, lane, ws); apply_diag(st, D + 1 * DIM, lane);
    apply_layer<1>(st, lane, ws); apply_diag(st, D + 2 * DIM, lane);
    apply_layer<2>(st, lane, ws); apply_diag(st, D + 3 * DIM, lane);
    apply_layer<3>(st, lane, ws); apply_diag(st, D + 4 * DIM, lane);
    apply_layer<4>(st, lane, ws); apply_diag(st, D + 5 * DIM, lane);
    apply_layer<5>(st, lane, ws);
    // (Dpost_5 is pure phase -> dropped; Ring_5 folded into W via T6)

    const float* W = ws + WS_W;
    float acc = 0.f;
#pragma unroll
    for (int v = 0; v < 16; ++v) {
        float p = st[v].x * st[v].x + st[v].y * st[v].y;
        acc = fmaf(p, W[(v << 6) | lane], acc);
    }
#pragma unroll
    for (int off = 32; off > 0; off >>= 1) acc += __shfl_down(acc, off, 64);
    if (lane == 0) out[b] = acc + fcb[0];
}

extern "C" void kernel_launch(void* const* d_in, const int* in_sizes, int n_in,
                              void* d_out, int out_size, void* d_ws, size_t ws_size,
                              hipStream_t stream) {
    const float* x   = (const float*)d_in[0];
    const float* qw  = (const float*)d_in[1];
    const float* fcw = (const float*)d_in[2];
    const float* fcb = (const float*)d_in[3];
    float* out = (float*)d_out;
    float* ws  = (float*)d_ws;

    prep_kernel<<<1, 1024, 0, stream>>>(qw, fcw, ws);
    qsim_kernel<<<BATCH / 4, 256, 0, stream>>>(x, ws, fcb, out);
}

// Round 8
// 332.312 us; speedup vs baseline: 6.3158x; 1.0147x over previous
//
#include <hip/hip_runtime.h>
#include <math.h>

#define NQ 10
#define DIM 1024
#define NLAYERS 6
#define BATCH 16384

// ============================================================================
// Compile-time GF(2) linear algebra.
// CNOT(c,t): psi'[i] = psi[L i], L = I + E_{pt,pc} (bit positions p = 9-qubit).
// A ring of CNOTs composes to K; we never apply it -- we relabel:
//   stored[j] = logical[T j],  T_{l+1} = K_l^{-1} T_l,  Tinv_{l+1} = Tinv_l K_l.
// Gate on qubit q at layer l acts on stored pairs j, j^m with
//   m = column_{9-q}(Tinv_l), role(j) = parity(row_{9-q}(T_l) & j).
// ============================================================================
struct F2Mat { unsigned short row[NQ]; };

constexpr F2Mat f2_id() {
    F2Mat m{}; for (int i = 0; i < NQ; ++i) m.row[i] = (unsigned short)(1u << i);
    return m;
}
constexpr F2Mat f2_mul(F2Mat A, F2Mat B) {
    F2Mat C{};
    for (int i = 0; i < NQ; ++i) {
        unsigned r = 0;
        for (int j = 0; j < NQ; ++j) if ((A.row[i] >> j) & 1u) r ^= B.row[j];
        C.row[i] = (unsigned short)r;
    }
    return C;
}
constexpr bool f2_is_id(F2Mat A) {
    for (int i = 0; i < NQ; ++i) if (A.row[i] != (1u << i)) return false;
    return true;
}
constexpr F2Mat L_mat(int pc, int pt) {
    F2Mat m = f2_id();
    m.row[pt] = (unsigned short)((1u << pt) | (1u << pc));
    return m;
}
constexpr F2Mat ring_K(int l) {
    int r = l % (NQ - 1) + 1;
    F2Mat K = f2_id();
    for (int w = 0; w < NQ; ++w) K = f2_mul(K, L_mat(NQ - 1 - w, NQ - 1 - (w + r) % NQ));
    return K;
}
constexpr F2Mat ring_Kinv(int l) {
    int r = l % (NQ - 1) + 1;
    F2Mat K = f2_id();
    for (int w = NQ - 1; w >= 0; --w) K = f2_mul(K, L_mat(NQ - 1 - w, NQ - 1 - (w + r) % NQ));
    return K;
}
struct Tables { F2Mat T[NLAYERS + 1]; F2Mat Tinv[NLAYERS]; };
constexpr Tables make_tables() {
    Tables t{};
    t.T[0] = f2_id();
    F2Mat tinv = f2_id();
    for (int l = 0; l < NLAYERS; ++l) {
        t.Tinv[l] = tinv;
        t.T[l + 1] = f2_mul(ring_Kinv(l), t.T[l]);
        tinv = f2_mul(tinv, ring_K(l));
    }
    return t;
}
static constexpr Tables TB = make_tables();
static_assert(f2_is_id(f2_mul(ring_K(0), ring_Kinv(0))), "ring inverse");
static_assert(f2_is_id(f2_mul(TB.T[1], TB.Tinv[1])), "T1*Tinv1");
static_assert(f2_is_id(f2_mul(TB.T[3], TB.Tinv[3])), "T3*Tinv3");
static_assert(f2_is_id(f2_mul(TB.T[5], TB.Tinv[5])), "T5*Tinv5");
constexpr unsigned f2_col(F2Mat M, int p) {
    unsigned m = 0;
    for (int i = 0; i < NQ; ++i) m |= (((unsigned)M.row[i] >> p) & 1u) << i;
    return m;
}
__constant__ Tables dTB = make_tables();

// ws layout (floats):
//   [0,120)          {cos(th/2), sin(th/2)} per (l,q)
//   [128, 12416)     6 diagonals, each float2[1024]  (head + 5 boundaries)
//   [12416, 13440)   W_stored[j] = sum_k fc[k]*(1-2*bit_{9-k}(T6 j))
#define WS_CS   0
#define WS_DIAG 128
#define WS_W    12416

__global__ __launch_bounds__(256) void prep_kernel(const float* __restrict__ qw,
                                                   const float* __restrict__ fcw,
                                                   float* __restrict__ ws) {
    const int j = blockIdx.x * 256 + threadIdx.x;  // 4 blocks x 256 = 1024
    if (j < NLAYERS * NQ) {
        float s, c;
        sincosf(0.5f * qw[3 * j + 1], &s, &c);
        ws[WS_CS + 2 * j]     = c;
        ws[WS_CS + 2 * j + 1] = s;
    }
    float w = 0.f;
#pragma unroll
    for (int k = 0; k < NQ; ++k) {
        int b = __popc(j & (int)dTB.T[NLAYERS].row[NQ - 1 - k]) & 1;
        w += fcw[k] * (float)(1 - 2 * b);
    }
    ws[WS_W + j] = w;

    float2* D = (float2*)(ws + WS_DIAG);
    {   // head: Dpre_0 at T0 = I
        float ang = 0.f;
#pragma unroll
        for (int q = 0; q < NQ; ++q) {
            int b = (j >> (NQ - 1 - q)) & 1;
            ang += qw[3 * q + 0] * (float)(1 - 2 * b);
        }
        float sn, cn;
        sincosf(-0.5f * ang, &sn, &cn);
        D[j] = make_float2(cn, sn);
    }
#pragma unroll
    for (int l = 0; l < NLAYERS - 1; ++l) {
        float ang = 0.f;
#pragma unroll
        for (int q = 0; q < NQ; ++q) {
            int b1 = __popc(j & (int)dTB.T[l].row[NQ - 1 - q]) & 1;       // omega_l
            ang += qw[3 * (l * NQ + q) + 2] * (float)(1 - 2 * b1);
            int b2 = __popc(j & (int)dTB.T[l + 1].row[NQ - 1 - q]) & 1;   // phi_{l+1}
            ang += qw[3 * ((l + 1) * NQ + q) + 0] * (float)(1 - 2 * b2);
        }
        float sn, cn;
        sincosf(-0.5f * ang, &sn, &cn);
        D[(l + 1) * DIM + j] = make_float2(cn, sn);
    }
}

__device__ __forceinline__ float2 shfl_xor2(float2 a, int mask) {
    return make_float2(__shfl_xor(a.x, mask, 64), __shfl_xor(a.y, mask, 64));
}

// One real Givens rotation on generalized qubit (L,Q), applied to BOTH
// independent batch-element streams (e=0,1). The two streams interleave in
// straight-line code -> shfl latency of one hides under FMAs of the other.
template<int L, int Q>
__device__ __forceinline__ void apply_gate(float2 st[2][16], int lane,
                                           const float* __restrict__ ws) {
    constexpr unsigned m     = f2_col(TB.Tinv[L], NQ - 1 - Q);
    constexpr unsigned mreg  = m >> 6;
    constexpr unsigned mlane = m & 63u;
    constexpr unsigned f     = TB.T[L].row[NQ - 1 - Q];
    constexpr unsigned flane = f & 63u;
    constexpr unsigned freg  = f >> 6;
    const float c = ws[WS_CS + 2 * (L * NQ + Q)];
    const float s = ws[WS_CS + 2 * (L * NQ + Q) + 1];
    float cs0;
    if constexpr (flane != 0) {
        int lp = __popc(lane & (int)flane) & 1;
        cs0 = lp ? s : -s;
    } else {
        cs0 = -s;
    }
    const float cs1 = -cs0;
    float2 olds[2][16];
#pragma unroll
    for (int e = 0; e < 2; ++e)
#pragma unroll
        for (int v = 0; v < 16; ++v) olds[e][v] = st[e][v];
#pragma unroll
    for (int v = 0; v < 16; ++v) {
        const float co = (__popc((int)(freg & (unsigned)v)) & 1) ? cs1 : cs0;
#pragma unroll
        for (int e = 0; e < 2; ++e) {
            float2 oth;
            if constexpr (mlane != 0) oth = shfl_xor2(olds[e][v ^ (int)mreg], (int)mlane);
            else                      oth = olds[e][v ^ (int)mreg];
            st[e][v] = make_float2(fmaf(co, oth.x, c * olds[e][v].x),
                                   fmaf(co, oth.y, c * olds[e][v].y));
        }
    }
}

template<int L>
__device__ __forceinline__ void apply_layer(float2 st[2][16], int lane,
                                            const float* __restrict__ ws) {
    apply_gate<L, 0>(st, lane, ws); apply_gate<L, 1>(st, lane, ws);
    apply_gate<L, 2>(st, lane, ws); apply_gate<L, 3>(st, lane, ws);
    apply_gate<L, 4>(st, lane, ws); apply_gate<L, 5>(st, lane, ws);
    apply_gate<L, 6>(st, lane, ws); apply_gate<L, 7>(st, lane, ws);
    apply_gate<L, 8>(st, lane, ws); apply_gate<L, 9>(st, lane, ws);
}

template<int L>
__device__ __forceinline__ void apply_layer_all(float2 st[2][16], int lane,
                                                const float* __restrict__ ws) {
    apply_layer<L>(st, lane, ws);
}

__device__ __forceinline__ void apply_diag(float2 st[2][16], const float2* __restrict__ g,
                                           int lane) {
#pragma unroll
    for (int v = 0; v < 16; ++v) {
        float2 G = g[(v << 6) | lane];   // one load, shared by both streams
#pragma unroll
        for (int e = 0; e < 2; ++e) {
            float2 a = st[e][v];
            st[e][v] = make_float2(fmaf(a.x, G.x, -(a.y * G.y)),
                                   fmaf(a.x, G.y,   a.y * G.x));
        }
    }
}

__global__ __launch_bounds__(256, 3) void qsim_kernel(const float* __restrict__ x,
                                                      const float* __restrict__ ws,
                                                      const float* __restrict__ fcb,
                                                      float* __restrict__ out) {
    const int lane = threadIdx.x & 63;
    const int wid  = threadIdx.x >> 6;
    const int b0   = blockIdx.x * 8 + wid * 2;   // this wave: elements b0, b0+1

    float2 st[2][16];
#pragma unroll
    for (int e = 0; e < 2; ++e) {
        float cq[NQ], sq[NQ];
#pragma unroll
        for (int q = 0; q < NQ; ++q) {
            float ss, cc;
            __sincosf(0.5f * x[(b0 + e) * NQ + q], &ss, &cc);
            sq[q] = ss; cq[q] = cc;
        }
#pragma unroll
        for (int v = 0; v < 16; ++v) {
            const int i = (v << 6) | lane;
            float mag = 1.f;
#pragma unroll
            for (int q = 0; q < NQ; ++q) {
                int bit = (i >> (NQ - 1 - q)) & 1;
                mag *= bit ? sq[q] : cq[q];
            }
            const int k = __popc(i) & 3;
            float re = (k == 0) ? mag : ((k == 2) ? -mag : 0.f);
            float im = (k == 1) ? -mag : ((k == 3) ? mag : 0.f);
            st[e][v] = make_float2(re, im);
        }
    }

    const float2* D = (const float2*)(ws + WS_DIAG);
    apply_diag(st, D, lane);                                        // Dpre_0
    apply_layer<0>(st, lane, ws); apply_diag(st, D + 1 * DIM, lane);
    apply_layer<1>(st, lane, ws); apply_diag(st, D + 2 * DIM, lane);
    apply_layer<2>(st, lane, ws); apply_diag(st, D + 3 * DIM, lane);
    apply_layer<3>(st, lane, ws); apply_diag(st, D + 4 * DIM, lane);
    apply_layer<4>(st, lane, ws); apply_diag(st, D + 5 * DIM, lane);
    apply_layer<5>(st, lane, ws);
    // (Dpost_5 is pure phase -> dropped; Ring_5 folded into W via T6)

    const float* W = ws + WS_W;
    float acc0 = 0.f, acc1 = 0.f;
#pragma unroll
    for (int v = 0; v < 16; ++v) {
        float w = W[(v << 6) | lane];    // one load, shared
        float p0 = st[0][v].x * st[0][v].x + st[0][v].y * st[0][v].y;
        float p1 = st[1][v].x * st[1][v].x + st[1][v].y * st[1][v].y;
        acc0 = fmaf(p0, w, acc0);
        acc1 = fmaf(p1, w, acc1);
    }
#pragma unroll
    for (int off = 32; off > 0; off >>= 1) {
        acc0 += __shfl_down(acc0, off, 64);
        acc1 += __shfl_down(acc1, off, 64);
    }
    if (lane == 0) {
        float bias = fcb[0];
        out[b0]     = acc0 + bias;
        out[b0 + 1] = acc1 + bias;
    }
}

extern "C" void kernel_launch(void* const* d_in, const int* in_sizes, int n_in,
                              void* d_out, int out_size, void* d_ws, size_t ws_size,
                              hipStream_t stream) {
    const float* x   = (const float*)d_in[0];
    const float* qw  = (const float*)d_in[1];
    const float* fcw = (const float*)d_in[2];
    const float* fcb = (const float*)d_in[3];
    float* out = (float*)d_out;
    float* ws  = (float*)d_ws;

    prep_kernel<<<4, 256, 0, stream>>>(qw, fcw, ws);
    qsim_kernel<<<BATCH / 8, 256, 0, stream>>>(x, ws, fcb, out);
}

// Round 12
// 197.651 us; speedup vs baseline: 10.6187x; 1.6813x over previous
//
#include <hip/hip_runtime.h>
#include <math.h>

#define NQ 10
#define DIM 1024
#define NLAYERS 6
#define BATCH 16384

// ============================================================================
// Layer l: 10 rotations (plain qubits) -> physical CNOT-ring permutation via
// wave-private LDS -> boundary diagonal.  Rot = D1*Y*D2; all D's collapse into
// per-layer diagonals (precomputed); Y = [[c,-s],[s,c]] real Givens.
// Ring: psi'[j] = psi[K_l j], K_l = product of CNOT index maps (GF(2) linear).
// Boundary diag (post-perm): Dt_l[j] = Dpre_{l+1}[j] * Dpost_l[K_l j].
// Final ring folds into readout: W[j] = wsum[K5inv j]; Dpost_5 is pure phase.
// ============================================================================
struct F2Mat { unsigned short row[NQ]; };

constexpr F2Mat f2_id() {
    F2Mat m{}; for (int i = 0; i < NQ; ++i) m.row[i] = (unsigned short)(1u << i);
    return m;
}
constexpr F2Mat f2_mul(F2Mat A, F2Mat B) {
    F2Mat C{};
    for (int i = 0; i < NQ; ++i) {
        unsigned r = 0;
        for (int j = 0; j < NQ; ++j) if ((A.row[i] >> j) & 1u) r ^= B.row[j];
        C.row[i] = (unsigned short)r;
    }
    return C;
}
constexpr F2Mat L_mat(int pc, int pt) {
    F2Mat m = f2_id();
    m.row[pt] = (unsigned short)((1u << pt) | (1u << pc));
    return m;
}
constexpr F2Mat ring_K(int l) {      // psi'[i] = psi[K i]
    int r = l % (NQ - 1) + 1;
    F2Mat K = f2_id();
    for (int w = 0; w < NQ; ++w) K = f2_mul(K, L_mat(NQ - 1 - w, NQ - 1 - (w + r) % NQ));
    return K;
}
constexpr F2Mat ring_Kinv(int l) {
    int r = l % (NQ - 1) + 1;
    F2Mat K = f2_id();
    for (int w = NQ - 1; w >= 0; --w) K = f2_mul(K, L_mat(NQ - 1 - w, NQ - 1 - (w + r) % NQ));
    return K;
}
constexpr unsigned kapply(F2Mat K, unsigned j) {
    unsigned r = 0;
    for (int i = 0; i < NQ; ++i) r |= (unsigned)(__builtin_popcount(K.row[i] & j) & 1) << i;
    return r;
}

// ---- conflict-free LDS addressing: slot(j) = j ^ mix(j>>6), mix linear 4->6b.
// Small constexpr palette; graceful fallback (rank deficiency = conflicts only,
// never incorrect).
struct Mix { unsigned mk[4]; };
constexpr unsigned mix_apply(Mix m, unsigned h) {
    unsigned r = 0;
    for (int b = 0; b < 4; ++b) if ((h >> b) & 1) r ^= m.mk[b];
    return r;
}
constexpr int rank_of(const unsigned (&v)[6]) {
    unsigned a[6] = {v[0], v[1], v[2], v[3], v[4], v[5]};
    int rank = 0;
    for (int bit = 5; bit >= 0; --bit) {
        int piv = -1;
        for (int i = rank; i < 6; ++i) if ((a[i] >> bit) & 1) { piv = i; break; }
        if (piv < 0) continue;
        unsigned t = a[piv]; a[piv] = a[rank]; a[rank] = t;
        for (int i = 0; i < 6; ++i) if (i != rank && ((a[i] >> bit) & 1)) a[i] ^= a[rank];
        ++rank;
    }
    return rank;
}
constexpr int read_rank(F2Mat K, Mix m) {
    unsigned img[6] = {};
    for (int b = 0; b < 6; ++b) {
        unsigned t = kapply(K, 1u << b);
        img[b] = (t ^ mix_apply(m, t >> 6)) & 63u;
    }
    return rank_of(img);
}
constexpr Mix mix_candidate(int a) {
    Mix m{{0, 0, 0, 0}};
    if (a == 0) return m;
    if (a <= 6) {
        for (int i = 0; i < 4; ++i) m.mk[i] = 1u << ((i + (a - 1)) % 6);
        return m;
    }
    for (int i = 0; i < 4; ++i)
        m.mk[i] = (1u << ((i + (a - 7)) % 6)) | (1u << ((i + (a - 7) + 3) % 6));
    return m;
}
constexpr Mix find_mix(F2Mat K) {
    Mix best{{0, 0, 0, 0}};
    int bestr = read_rank(K, best);
    for (int a = 1; a < 13 && bestr < 6; ++a) {
        Mix c = mix_candidate(a);
        int r = read_rank(K, c);
        if (r > bestr) { best = c; bestr = r; }
    }
    return best;
}
struct RelayTabs { unsigned wb[16]; unsigned rb[16]; unsigned ck[6]; };
constexpr RelayTabs make_relay(int l) {
    F2Mat K = ring_K(l);
    Mix mx = find_mix(K);
    RelayTabs t{};
    for (int v = 0; v < 16; ++v) {
        t.wb[v] = ((unsigned)v << 6) ^ mix_apply(mx, (unsigned)v);
        unsigned kv = kapply(K, (unsigned)v << 6);
        t.rb[v] = kv ^ mix_apply(mx, kv >> 6);
    }
    for (int b = 0; b < 6; ++b) {
        unsigned kb = kapply(K, 1u << b);
        t.ck[b] = kb ^ mix_apply(mx, kb >> 6);
    }
    return t;
}

// runtime K tables for prep
struct DevTabs { unsigned short K[NLAYERS - 1][NQ]; unsigned short K5i[NQ]; };
constexpr DevTabs make_devtabs() {
    DevTabs d{};
    for (int l = 0; l < NLAYERS - 1; ++l) {
        F2Mat K = ring_K(l);
        for (int i = 0; i < NQ; ++i) d.K[l][i] = K.row[i];
    }
    F2Mat K5 = ring_Kinv(NLAYERS - 1);
    for (int i = 0; i < NQ; ++i) d.K5i[i] = K5.row[i];
    return d;
}
__constant__ DevTabs dKT = make_devtabs();
__device__ __forceinline__ unsigned kap_rt(const unsigned short* rows, unsigned j) {
    unsigned r = 0;
#pragma unroll
    for (int i = 0; i < NQ; ++i) r |= (unsigned)(__popc((unsigned)rows[i] & j) & 1) << i;
    return r;
}

// ws layout (floats):
//   [0,120)          {cos(th/2), sin(th/2)} per (l,q)
//   [128, 12416)     6 diagonals, float2[1024] each (head Dpre_0 + 5 boundary)
//   [12416, 13440)   W[j] = sum_k fc[k]*(1-2*bit_{9-k}(K5inv j))
#define WS_CS   0
#define WS_DIAG 128
#define WS_W    12416

__global__ __launch_bounds__(256) void prep_kernel(const float* __restrict__ qw,
                                                   const float* __restrict__ fcw,
                                                   float* __restrict__ ws) {
    const int j = blockIdx.x * 256 + threadIdx.x;  // 4 blocks x 256 = 1024
    if (j < NLAYERS * NQ) {
        float s, c;
        sincosf(0.5f * qw[3 * j + 1], &s, &c);
        ws[WS_CS + 2 * j]     = c;
        ws[WS_CS + 2 * j + 1] = s;
    }
    {   // readout with final ring folded in
        unsigned jj = kap_rt(dKT.K5i, (unsigned)j);
        float w = 0.f;
#pragma unroll
        for (int k = 0; k < NQ; ++k)
            w += fcw[k] * (float)(1 - 2 * (int)((jj >> (NQ - 1 - k)) & 1u));
        ws[WS_W + j] = w;
    }
    float2* D = (float2*)(ws + WS_DIAG);
    {   // head: Dpre_0
        float ang = 0.f;
#pragma unroll
        for (int q = 0; q < NQ; ++q)
            ang += qw[3 * q + 0] * (float)(1 - 2 * (int)((j >> (NQ - 1 - q)) & 1));
        float sn, cn; sincosf(-0.5f * ang, &sn, &cn);
        D[j] = make_float2(cn, sn);
    }
#pragma unroll
    for (int l = 0; l < NLAYERS - 1; ++l) {  // Dt_l[j] = Dpre_{l+1}[j]*Dpost_l[K_l j]
        unsigned kj = kap_rt(dKT.K[l], (unsigned)j);
        float ang = 0.f;
#pragma unroll
        for (int q = 0; q < NQ; ++q) {
            ang += qw[3 * ((l + 1) * NQ + q) + 0] * (float)(1 - 2 * (int)(((unsigned)j >> (NQ - 1 - q)) & 1u));
            ang += qw[3 * (l * NQ + q) + 2]       * (float)(1 - 2 * (int)((kj >> (NQ - 1 - q)) & 1u));
        }
        float sn, cn; sincosf(-0.5f * ang, &sn, &cn);
        D[(l + 1) * DIM + j] = make_float2(cn, sn);
    }
}

// ---------------- gates ----------------
// reg-bit gate (index bit P>=6): pairs across v
template<int P>
__device__ __forceinline__ void gate_reg(float2 st[2][16], float c, float s) {
    constexpr int vm = 1 << (P - 6);
#pragma unroll
    for (int v = 0; v < 16; ++v) {
        if (v & vm) continue;
#pragma unroll
        for (int e = 0; e < 2; ++e) {
            float2 a = st[e][v], b = st[e][v | vm];
            st[e][v]      = make_float2(fmaf(-s, b.x, c * a.x), fmaf(-s, b.y, c * a.y));
            st[e][v | vm] = make_float2(fmaf( s, a.x, c * b.x), fmaf( s, a.y, c * b.y));
        }
    }
}

// lane masks 1,2 via DPP quad_perm; 4,8,16 via ds_swizzle (documented encodings)
template<int CTRL>
__device__ __forceinline__ float dpp_x(float x) {
    return __int_as_float(__builtin_amdgcn_update_dpp(__float_as_int(x), __float_as_int(x),
                                                      CTRL, 0xF, 0xF, true));
}
template<int MASK>
__device__ __forceinline__ float lane_xor(float x) {
    if constexpr (MASK == 1)      return dpp_x<0xB1>(x);              // quad_perm [1,0,3,2]
    else if constexpr (MASK == 2) return dpp_x<0x4E>(x);              // quad_perm [2,3,0,1]
    else if constexpr (MASK == 4) return __int_as_float(__builtin_amdgcn_ds_swizzle(__float_as_int(x), 0x101F));
    else if constexpr (MASK == 8) return __int_as_float(__builtin_amdgcn_ds_swizzle(__float_as_int(x), 0x201F));
    else                          return __int_as_float(__builtin_amdgcn_ds_swizzle(__float_as_int(x), 0x401F));
}
template<int MASK>
__device__ __forceinline__ void gate_lane(float2 st[2][16], int lane, float c, float s) {
    const float co = (lane & MASK) ? s : -s;   // coeff on partner value
#pragma unroll
    for (int v = 0; v < 16; ++v)
#pragma unroll
        for (int e = 0; e < 2; ++e) {
            float2 a = st[e][v];
            float ox = lane_xor<MASK>(a.x), oy = lane_xor<MASK>(a.y);
            st[e][v] = make_float2(fmaf(co, ox, c * a.x), fmaf(co, oy, c * a.y));
        }
}

// lane mask 32 via ds_bpermute (full 64-lane pull; proven primitive behind
// __shfl_xor(x,32,64) in the passing rounds 5-8).
__device__ __forceinline__ float bperm32(float x, int addr) {
    return __int_as_float(__builtin_amdgcn_ds_bpermute(addr, __float_as_int(x)));
}
__device__ __forceinline__ void gate_mask32(float2 st[2][16], int lane, float c, float s) {
    const float co = (lane & 32) ? s : -s;     // coeff on partner value
    const int addr = (lane ^ 32) << 2;
#pragma unroll
    for (int v = 0; v < 16; ++v)
#pragma unroll
        for (int e = 0; e < 2; ++e) {
            float2 a = st[e][v];
            float ox = bperm32(a.x, addr), oy = bperm32(a.y, addr);
            st[e][v] = make_float2(fmaf(co, ox, c * a.x), fmaf(co, oy, c * a.y));
        }
}

// physical ring permutation via wave-private LDS: st'[j] = st[K_L j]
template<int L>
__device__ __forceinline__ void relayout(float2 st[2][16], int lane, float2* buf) {
    constexpr RelayTabs RT = make_relay(L);
    unsigned rl = 0;
#pragma unroll
    for (int b = 0; b < 6; ++b) rl ^= ((lane >> b) & 1) ? RT.ck[b] : 0u;
#pragma unroll
    for (int e = 0; e < 2; ++e) {
#pragma unroll
        for (int v = 0; v < 16; ++v) buf[RT.wb[v] ^ (unsigned)lane] = st[e][v];
        asm volatile("s_waitcnt lgkmcnt(0)" ::: "memory");
#pragma unroll
        for (int v = 0; v < 16; ++v) st[e][v] = buf[RT.rb[v] ^ rl];
    }
}

__device__ __forceinline__ void apply_diag(float2 st[2][16], const float2* __restrict__ g,
                                           int lane) {
#pragma unroll
    for (int v = 0; v < 16; ++v) {
        float2 G = g[(v << 6) | lane];
#pragma unroll
        for (int e = 0; e < 2; ++e) {
            float2 a = st[e][v];
            st[e][v] = make_float2(fmaf(a.x, G.x, -(a.y * G.y)),
                                   fmaf(a.x, G.y,   a.y * G.x));
        }
    }
}

template<int L>
__device__ __forceinline__ void do_layer(float2 st[2][16], int lane,
                                         const float* __restrict__ ws, float2* buf) {
    const float* cs = ws + WS_CS + 2 * (L * NQ);
    gate_reg<9>(st, cs[0], cs[1]);            // q0
    gate_reg<8>(st, cs[2], cs[3]);            // q1
    gate_reg<7>(st, cs[4], cs[5]);            // q2
    gate_reg<6>(st, cs[6], cs[7]);            // q3
    gate_mask32(st, lane, cs[8], cs[9]);      // q4 (bit 5)
    gate_lane<16>(st, lane, cs[10], cs[11]);  // q5
    gate_lane<8>(st, lane, cs[12], cs[13]);   // q6
    gate_lane<4>(st, lane, cs[14], cs[15]);   // q7
    gate_lane<2>(st, lane, cs[16], cs[17]);   // q8
    gate_lane<1>(st, lane, cs[18], cs[19]);   // q9
    if constexpr (L < NLAYERS - 1) {
        relayout<L>(st, lane, buf);
        apply_diag(st, (const float2*)(ws + WS_DIAG) + (L + 1) * DIM, lane);
    }
}

__global__ __launch_bounds__(256, 4) void qsim_kernel(const float* __restrict__ x,
                                                      const float* __restrict__ ws,
                                                      const float* __restrict__ fcb,
                                                      float* __restrict__ out) {
    __shared__ float2 lbuf[4][DIM];
    const int lane = threadIdx.x & 63;
    const int wid  = threadIdx.x >> 6;
    const int b0   = blockIdx.x * 8 + wid * 2;
    float2* buf = lbuf[wid];

    float2 st[2][16];
#pragma unroll
    for (int e = 0; e < 2; ++e) {
        float cq[NQ], sq[NQ];
#pragma unroll
        for (int q = 0; q < NQ; ++q) {
            float ss, cc;
            __sincosf(0.5f * x[(b0 + e) * NQ + q], &ss, &cc);
            sq[q] = ss; cq[q] = cc;
        }
#pragma unroll
        for (int v = 0; v < 16; ++v) {
            const int i = (v << 6) | lane;
            float mag = 1.f;
#pragma unroll
            for (int q = 0; q < NQ; ++q) {
                int bit = (i >> (NQ - 1 - q)) & 1;
                mag *= bit ? sq[q] : cq[q];
            }
            const int k = __popc(i) & 3;
            float re = (k == 0) ? mag : ((k == 2) ? -mag : 0.f);
            float im = (k == 1) ? -mag : ((k == 3) ? mag : 0.f);
            st[e][v] = make_float2(re, im);
        }
    }

    apply_diag(st, (const float2*)(ws + WS_DIAG), lane);   // Dpre_0
    do_layer<0>(st, lane, ws, buf);
    do_layer<1>(st, lane, ws, buf);
    do_layer<2>(st, lane, ws, buf);
    do_layer<3>(st, lane, ws, buf);
    do_layer<4>(st, lane, ws, buf);
    do_layer<5>(st, lane, ws, buf);   // no relayout/diag (folded into W / dropped)

    const float* W = ws + WS_W;
    float acc0 = 0.f, acc1 = 0.f;
#pragma unroll
    for (int v = 0; v < 16; ++v) {
        float w = W[(v << 6) | lane];
        float p0 = st[0][v].x * st[0][v].x + st[0][v].y * st[0][v].y;
        float p1 = st[1][v].x * st[1][v].x + st[1][v].y * st[1][v].y;
        acc0 = fmaf(p0, w, acc0);
        acc1 = fmaf(p1, w, acc1);
    }
#pragma unroll
    for (int off = 32; off > 0; off >>= 1) {
        acc0 += __shfl_down(acc0, off, 64);
        acc1 += __shfl_down(acc1, off, 64);
    }
    if (lane == 0) {
        float bias = fcb[0];
        out[b0]     = acc0 + bias;
        out[b0 + 1] = acc1 + bias;
    }
}

extern "C" void kernel_launch(void* const* d_in, const int* in_sizes, int n_in,
                              void* d_out, int out_size, void* d_ws, size_t ws_size,
                              hipStream_t stream) {
    const float* x   = (const float*)d_in[0];
    const float* qw  = (const float*)d_in[1];
    const float* fcw = (const float*)d_in[2];
    const float* fcb = (const float*)d_in[3];
    float* out = (float*)d_out;
    float* ws  = (float*)d_ws;

    prep_kernel<<<4, 256, 0, stream>>>(qw, fcw, ws);
    qsim_kernel<<<BATCH / 8, 256, 0, stream>>>(x, ws, fcb, out);
}

// Round 13
// 184.045 us; speedup vs baseline: 11.4037x; 1.0739x over previous
//
#include <hip/hip_runtime.h>
#include <math.h>

#define NQ 10
#define DIM 1024
#define NLAYERS 6
#define BATCH 16384

typedef float v2f __attribute__((ext_vector_type(2)));

// ============================================================================
// Layer l: 10 rotations (plain qubits) -> physical CNOT-ring permutation via
// wave-private LDS -> boundary diagonal.  Rot = D1*Y*D2; diagonals collapse
// into per-layer diagonals (precomputed); Y = [[c,-s],[s,c]] real Givens.
// Ring: psi'[j] = psi[K_l j]; boundary diag Dt_l[j] = Dpre_{l+1}[j]*Dpost_l[K_l j];
// final ring folds into readout W[j] = wsum[K5inv j]; Dpost_5 pure phase.
// All complex updates use REAL shared scalars -> v_pk_fma_f32 packed math.
// ============================================================================
struct F2Mat { unsigned short row[NQ]; };

constexpr F2Mat f2_id() {
    F2Mat m{}; for (int i = 0; i < NQ; ++i) m.row[i] = (unsigned short)(1u << i);
    return m;
}
constexpr F2Mat f2_mul(F2Mat A, F2Mat B) {
    F2Mat C{};
    for (int i = 0; i < NQ; ++i) {
        unsigned r = 0;
        for (int j = 0; j < NQ; ++j) if ((A.row[i] >> j) & 1u) r ^= B.row[j];
        C.row[i] = (unsigned short)r;
    }
    return C;
}
constexpr F2Mat L_mat(int pc, int pt) {
    F2Mat m = f2_id();
    m.row[pt] = (unsigned short)((1u << pt) | (1u << pc));
    return m;
}
constexpr F2Mat ring_K(int l) {      // psi'[i] = psi[K i]
    int r = l % (NQ - 1) + 1;
    F2Mat K = f2_id();
    for (int w = 0; w < NQ; ++w) K = f2_mul(K, L_mat(NQ - 1 - w, NQ - 1 - (w + r) % NQ));
    return K;
}
constexpr F2Mat ring_Kinv(int l) {
    int r = l % (NQ - 1) + 1;
    F2Mat K = f2_id();
    for (int w = NQ - 1; w >= 0; --w) K = f2_mul(K, L_mat(NQ - 1 - w, NQ - 1 - (w + r) % NQ));
    return K;
}
constexpr unsigned kapply(F2Mat K, unsigned j) {
    unsigned r = 0;
    for (int i = 0; i < NQ; ++i) r |= (unsigned)(__builtin_popcount(K.row[i] & j) & 1) << i;
    return r;
}

// ---- conflict-free LDS addressing: slot(j) = j ^ mix(j>>6), mix linear 4->6b.
struct Mix { unsigned mk[4]; };
constexpr unsigned mix_apply(Mix m, unsigned h) {
    unsigned r = 0;
    for (int b = 0; b < 4; ++b) if ((h >> b) & 1) r ^= m.mk[b];
    return r;
}
constexpr int rank_of(const unsigned (&v)[6]) {
    unsigned a[6] = {v[0], v[1], v[2], v[3], v[4], v[5]};
    int rank = 0;
    for (int bit = 5; bit >= 0; --bit) {
        int piv = -1;
        for (int i = rank; i < 6; ++i) if ((a[i] >> bit) & 1) { piv = i; break; }
        if (piv < 0) continue;
        unsigned t = a[piv]; a[piv] = a[rank]; a[rank] = t;
        for (int i = 0; i < 6; ++i) if (i != rank && ((a[i] >> bit) & 1)) a[i] ^= a[rank];
        ++rank;
    }
    return rank;
}
constexpr int read_rank(F2Mat K, Mix m) {
    unsigned img[6] = {};
    for (int b = 0; b < 6; ++b) {
        unsigned t = kapply(K, 1u << b);
        img[b] = (t ^ mix_apply(m, t >> 6)) & 63u;
    }
    return rank_of(img);
}
constexpr Mix mix_candidate(int a) {
    Mix m{{0, 0, 0, 0}};
    if (a == 0) return m;
    if (a <= 6) {
        for (int i = 0; i < 4; ++i) m.mk[i] = 1u << ((i + (a - 1)) % 6);
        return m;
    }
    for (int i = 0; i < 4; ++i)
        m.mk[i] = (1u << ((i + (a - 7)) % 6)) | (1u << ((i + (a - 7) + 3) % 6));
    return m;
}
constexpr Mix find_mix(F2Mat K) {
    Mix best{{0, 0, 0, 0}};
    int bestr = read_rank(K, best);
    for (int a = 1; a < 13 && bestr < 6; ++a) {
        Mix c = mix_candidate(a);
        int r = read_rank(K, c);
        if (r > bestr) { best = c; bestr = r; }
    }
    return best;
}
struct RelayTabs { unsigned wb[16]; unsigned rb[16]; unsigned ck[6]; };
constexpr RelayTabs make_relay(int l) {
    F2Mat K = ring_K(l);
    Mix mx = find_mix(K);
    RelayTabs t{};
    for (int v = 0; v < 16; ++v) {
        t.wb[v] = ((unsigned)v << 6) ^ mix_apply(mx, (unsigned)v);
        unsigned kv = kapply(K, (unsigned)v << 6);
        t.rb[v] = kv ^ mix_apply(mx, kv >> 6);
    }
    for (int b = 0; b < 6; ++b) {
        unsigned kb = kapply(K, 1u << b);
        t.ck[b] = kb ^ mix_apply(mx, kb >> 6);
    }
    return t;
}

// runtime K tables for prep
struct DevTabs { unsigned short K[NLAYERS - 1][NQ]; unsigned short K5i[NQ]; };
constexpr DevTabs make_devtabs() {
    DevTabs d{};
    for (int l = 0; l < NLAYERS - 1; ++l) {
        F2Mat K = ring_K(l);
        for (int i = 0; i < NQ; ++i) d.K[l][i] = K.row[i];
    }
    F2Mat K5 = ring_Kinv(NLAYERS - 1);
    for (int i = 0; i < NQ; ++i) d.K5i[i] = K5.row[i];
    return d;
}
__constant__ DevTabs dKT = make_devtabs();
__device__ __forceinline__ unsigned kap_rt(const unsigned short* rows, unsigned j) {
    unsigned r = 0;
#pragma unroll
    for (int i = 0; i < NQ; ++i) r |= (unsigned)(__popc((unsigned)rows[i] & j) & 1) << i;
    return r;
}

// ws layout (floats):
//   [0,120)          {cos(th/2), sin(th/2)} per (l,q)
//   [128, 12416)     6 diagonals, float2[1024] each (head Dpre_0 + 5 boundary)
//   [12416, 13440)   W[j] = sum_k fc[k]*(1-2*bit_{9-k}(K5inv j))
#define WS_CS   0
#define WS_DIAG 128
#define WS_W    12416

// 24 blocks x 256: part = bid>>2 (0: cs+W+head diag; 1..5: boundary diag l-1),
// j = (bid&3)*256 + tid.
__global__ __launch_bounds__(256) void prep_kernel(const float* __restrict__ qw,
                                                   const float* __restrict__ fcw,
                                                   float* __restrict__ ws) {
    const int part = blockIdx.x >> 2;
    const int j = (blockIdx.x & 3) * 256 + threadIdx.x;
    float2* D = (float2*)(ws + WS_DIAG);
    if (part == 0) {
        if (j < NLAYERS * NQ) {
            float s, c;
            sincosf(0.5f * qw[3 * j + 1], &s, &c);
            ws[WS_CS + 2 * j]     = c;
            ws[WS_CS + 2 * j + 1] = s;
        }
        {   // readout with final ring folded in
            unsigned jj = kap_rt(dKT.K5i, (unsigned)j);
            float w = 0.f;
#pragma unroll
            for (int k = 0; k < NQ; ++k)
                w += fcw[k] * (float)(1 - 2 * (int)((jj >> (NQ - 1 - k)) & 1u));
            ws[WS_W + j] = w;
        }
        {   // head: Dpre_0
            float ang = 0.f;
#pragma unroll
            for (int q = 0; q < NQ; ++q)
                ang += qw[3 * q + 0] * (float)(1 - 2 * (int)((j >> (NQ - 1 - q)) & 1));
            float sn, cn; sincosf(-0.5f * ang, &sn, &cn);
            D[j] = make_float2(cn, sn);
        }
    } else {
        const int l = part - 1;                  // boundary l: Dt_l
        unsigned kj = kap_rt(dKT.K[l], (unsigned)j);
        float ang = 0.f;
#pragma unroll
        for (int q = 0; q < NQ; ++q) {
            ang += qw[3 * ((l + 1) * NQ + q) + 0] * (float)(1 - 2 * (int)(((unsigned)j >> (NQ - 1 - q)) & 1u));
            ang += qw[3 * (l * NQ + q) + 2]       * (float)(1 - 2 * (int)((kj >> (NQ - 1 - q)) & 1u));
        }
        float sn, cn; sincosf(-0.5f * ang, &sn, &cn);
        D[(l + 1) * DIM + j] = make_float2(cn, sn);
    }
}

// ---------------- gates (packed f32: coefficients REAL + shared on .x/.y) ----
// reg-bit gate (index bit P>=6): pairs across v
template<int P>
__device__ __forceinline__ void gate_reg(v2f st[2][16], float c, float s) {
    constexpr int vm = 1 << (P - 6);
#pragma unroll
    for (int v = 0; v < 16; ++v) {
        if (v & vm) continue;
#pragma unroll
        for (int e = 0; e < 2; ++e) {
            v2f a = st[e][v], b = st[e][v | vm];
            st[e][v]      = c * a - s * b;   // v_pk_mul + v_pk_fma
            st[e][v | vm] = s * a + c * b;
        }
    }
}

// lane masks 1,2 via DPP quad_perm; 4,8,16 via ds_swizzle (documented encodings)
template<int CTRL>
__device__ __forceinline__ float dpp_x(float x) {
    return __int_as_float(__builtin_amdgcn_update_dpp(__float_as_int(x), __float_as_int(x),
                                                      CTRL, 0xF, 0xF, true));
}
template<int MASK>
__device__ __forceinline__ float lane_xor(float x) {
    if constexpr (MASK == 1)      return dpp_x<0xB1>(x);              // quad_perm [1,0,3,2]
    else if constexpr (MASK == 2) return dpp_x<0x4E>(x);              // quad_perm [2,3,0,1]
    else if constexpr (MASK == 4) return __int_as_float(__builtin_amdgcn_ds_swizzle(__float_as_int(x), 0x101F));
    else if constexpr (MASK == 8) return __int_as_float(__builtin_amdgcn_ds_swizzle(__float_as_int(x), 0x201F));
    else                          return __int_as_float(__builtin_amdgcn_ds_swizzle(__float_as_int(x), 0x401F));
}
template<int MASK>
__device__ __forceinline__ void gate_lane(v2f st[2][16], int lane, float c, float s) {
    const float co = (lane & MASK) ? s : -s;   // coeff on partner value
#pragma unroll
    for (int v = 0; v < 16; ++v)
#pragma unroll
        for (int e = 0; e < 2; ++e) {
            v2f a = st[e][v];
            v2f o;
            o.x = lane_xor<MASK>(a.x);
            o.y = lane_xor<MASK>(a.y);
            st[e][v] = c * a + co * o;        // v_pk_mul + v_pk_fma
        }
}

// lane mask 32 via ds_bpermute (proven primitive from passing rounds)
__device__ __forceinline__ float bperm32(float x, int addr) {
    return __int_as_float(__builtin_amdgcn_ds_bpermute(addr, __float_as_int(x)));
}
__device__ __forceinline__ void gate_mask32(v2f st[2][16], int lane, float c, float s) {
    const float co = (lane & 32) ? s : -s;
    const int addr = (lane ^ 32) << 2;
#pragma unroll
    for (int v = 0; v < 16; ++v)
#pragma unroll
        for (int e = 0; e < 2; ++e) {
            v2f a = st[e][v];
            v2f o;
            o.x = bperm32(a.x, addr);
            o.y = bperm32(a.y, addr);
            st[e][v] = c * a + co * o;
        }
}

// physical ring permutation via wave-private LDS: st'[j] = st[K_L j]
template<int L>
__device__ __forceinline__ void relayout(v2f st[2][16], int lane, v2f* buf) {
    constexpr RelayTabs RT = make_relay(L);
    unsigned rl = 0;
#pragma unroll
    for (int b = 0; b < 6; ++b) rl ^= ((lane >> b) & 1) ? RT.ck[b] : 0u;
#pragma unroll
    for (int e = 0; e < 2; ++e) {
#pragma unroll
        for (int v = 0; v < 16; ++v) buf[RT.wb[v] ^ (unsigned)lane] = st[e][v];
        asm volatile("s_waitcnt lgkmcnt(0)" ::: "memory");
#pragma unroll
        for (int v = 0; v < 16; ++v) st[e][v] = buf[RT.rb[v] ^ rl];
    }
}

// complex diag multiply: r = a.xx*G + a.yy*(-G.y, G.x)  (2 pk ops/stream)
__device__ __forceinline__ void apply_diag(v2f st[2][16], const v2f* __restrict__ g,
                                           int lane) {
#pragma unroll
    for (int v = 0; v < 16; ++v) {
        v2f G = g[(v << 6) | lane];
        v2f nG; nG.x = -G.y; nG.y = G.x;      // shared by both streams
#pragma unroll
        for (int e = 0; e < 2; ++e) {
            v2f a = st[e][v];
            st[e][v] = a.xx * G + a.yy * nG;
        }
    }
}

template<int L>
__device__ __forceinline__ void do_layer(v2f st[2][16], int lane,
                                         const float* __restrict__ ws, v2f* buf) {
    const float* cs = ws + WS_CS + 2 * (L * NQ);
    gate_reg<9>(st, cs[0], cs[1]);            // q0
    gate_reg<8>(st, cs[2], cs[3]);            // q1
    gate_reg<7>(st, cs[4], cs[5]);            // q2
    gate_reg<6>(st, cs[6], cs[7]);            // q3
    gate_mask32(st, lane, cs[8], cs[9]);      // q4 (bit 5)
    gate_lane<16>(st, lane, cs[10], cs[11]);  // q5
    gate_lane<8>(st, lane, cs[12], cs[13]);   // q6
    gate_lane<4>(st, lane, cs[14], cs[15]);   // q7
    gate_lane<2>(st, lane, cs[16], cs[17]);   // q8
    gate_lane<1>(st, lane, cs[18], cs[19]);   // q9
    if constexpr (L < NLAYERS - 1) {
        relayout<L>(st, lane, buf);
        apply_diag(st, (const v2f*)(ws + WS_DIAG) + (L + 1) * DIM, lane);
    }
}

__global__ __launch_bounds__(256, 4) void qsim_kernel(const float* __restrict__ x,
                                                      const float* __restrict__ ws,
                                                      const float* __restrict__ fcb,
                                                      float* __restrict__ out) {
    __shared__ v2f lbuf[4][DIM];
    const int lane = threadIdx.x & 63;
    const int wid  = threadIdx.x >> 6;
    const int b0   = blockIdx.x * 8 + wid * 2;
    v2f* buf = lbuf[wid];

    v2f st[2][16];
#pragma unroll
    for (int e = 0; e < 2; ++e) {
        float cq[NQ], sq[NQ];
#pragma unroll
        for (int q = 0; q < NQ; ++q) {
            float ss, cc;
            __sincosf(0.5f * x[(b0 + e) * NQ + q], &ss, &cc);
            sq[q] = ss; cq[q] = cc;
        }
#pragma unroll
        for (int v = 0; v < 16; ++v) {
            const int i = (v << 6) | lane;
            float mag = 1.f;
#pragma unroll
            for (int q = 0; q < NQ; ++q) {
                int bit = (i >> (NQ - 1 - q)) & 1;
                mag *= bit ? sq[q] : cq[q];
            }
            const int k = __popc(i) & 3;
            float re = (k == 0) ? mag : ((k == 2) ? -mag : 0.f);
            float im = (k == 1) ? -mag : ((k == 3) ? mag : 0.f);
            v2f a; a.x = re; a.y = im;
            st[e][v] = a;
        }
    }

    apply_diag(st, (const v2f*)(ws + WS_DIAG), lane);      // Dpre_0
    do_layer<0>(st, lane, ws, buf);
    do_layer<1>(st, lane, ws, buf);
    do_layer<2>(st, lane, ws, buf);
    do_layer<3>(st, lane, ws, buf);
    do_layer<4>(st, lane, ws, buf);
    do_layer<5>(st, lane, ws, buf);   // no relayout/diag (folded into W / dropped)

    const float* W = ws + WS_W;
    float acc0 = 0.f, acc1 = 0.f;
#pragma unroll
    for (int v = 0; v < 16; ++v) {
        float w = W[(v << 6) | lane];
        float p0 = st[0][v].x * st[0][v].x + st[0][v].y * st[0][v].y;
        float p1 = st[1][v].x * st[1][v].x + st[1][v].y * st[1][v].y;
        acc0 = fmaf(p0, w, acc0);
        acc1 = fmaf(p1, w, acc1);
    }
#pragma unroll
    for (int off = 32; off > 0; off >>= 1) {
        acc0 += __shfl_down(acc0, off, 64);
        acc1 += __shfl_down(acc1, off, 64);
    }
    if (lane == 0) {
        float bias = fcb[0];
        out[b0]     = acc0 + bias;
        out[b0 + 1] = acc1 + bias;
    }
}

extern "C" void kernel_launch(void* const* d_in, const int* in_sizes, int n_in,
                              void* d_out, int out_size, void* d_ws, size_t ws_size,
                              hipStream_t stream) {
    const float* x   = (const float*)d_in[0];
    const float* qw  = (const float*)d_in[1];
    const float* fcw = (const float*)d_in[2];
    const float* fcb = (const float*)d_in[3];
    float* out = (float*)d_out;
    float* ws  = (float*)d_ws;

    prep_kernel<<<24, 256, 0, stream>>>(qw, fcw, ws);
    qsim_kernel<<<BATCH / 8, 256, 0, stream>>>(x, ws, fcb, out);
}

// Round 15
// 183.466 us; speedup vs baseline: 11.4397x; 1.0032x over previous
//
#include <hip/hip_runtime.h>
#include <math.h>

#define NQ 10
#define DIM 1024
#define NLAYERS 6
#define BATCH 16384

typedef float v2f __attribute__((ext_vector_type(2)));

// ============================================================================
// Per layer: q0-q3 reg gates -> S-relayout (swap storage bits 9..6 <-> 5..2)
// -> q4-q7 reg gates -> q8,q9 DPP lane gates -> relayout M = S*K_l (restores
// canonical layout AND applies the CNOT ring) -> boundary diagonal.
// Layer 5: no trailing relayout; readout folds S and ring5 into W.
// Rot = D1*Y*D2; diagonals collapse into per-layer diagonals (precomputed).
// All updates are complex-value x real-shared-scalar -> v_pk_*_f32 packed.
// ============================================================================
struct F2Mat { unsigned short row[NQ]; };

constexpr F2Mat f2_id() {
    F2Mat m{}; for (int i = 0; i < NQ; ++i) m.row[i] = (unsigned short)(1u << i);
    return m;
}
constexpr F2Mat f2_mul(F2Mat A, F2Mat B) {
    F2Mat C{};
    for (int i = 0; i < NQ; ++i) {
        unsigned r = 0;
        for (int j = 0; j < NQ; ++j) if ((A.row[i] >> j) & 1u) r ^= B.row[j];
        C.row[i] = (unsigned short)r;
    }
    return C;
}
constexpr F2Mat L_mat(int pc, int pt) {
    F2Mat m = f2_id();
    m.row[pt] = (unsigned short)((1u << pt) | (1u << pc));
    return m;
}
constexpr F2Mat ring_K(int l) {      // psi'[i] = psi[K i]
    int r = l % (NQ - 1) + 1;
    F2Mat K = f2_id();
    for (int w = 0; w < NQ; ++w) K = f2_mul(K, L_mat(NQ - 1 - w, NQ - 1 - (w + r) % NQ));
    return K;
}
constexpr F2Mat ring_Kinv(int l) {
    int r = l % (NQ - 1) + 1;
    F2Mat K = f2_id();
    for (int w = NQ - 1; w >= 0; --w) K = f2_mul(K, L_mat(NQ - 1 - w, NQ - 1 - (w + r) % NQ));
    return K;
}
constexpr unsigned kapply(F2Mat K, unsigned j) {
    unsigned r = 0;
    for (int i = 0; i < NQ; ++i) r |= (unsigned)(__builtin_popcount(K.row[i] & j) & 1) << i;
    return r;
}

// bit-swap permutation S: exchange bit positions {9,8,7,6} <-> {5,4,3,2}
constexpr int s_bit(int i) { return (i >= 2 && i <= 5) ? i + 4 : (i >= 6 && i <= 9) ? i - 4 : i; }
constexpr F2Mat S_mat() {
    F2Mat m{};
    for (int i = 0; i < NQ; ++i) m.row[i] = (unsigned short)(1u << s_bit(i));
    return m;
}
// M = S*K_l  (j -> S(K j)); bit i of S(x) = bit s(i) of x
constexpr F2Mat SK_mat(int l) {
    F2Mat K = ring_K(l);
    F2Mat m{};
    for (int i = 0; i < NQ; ++i) m.row[i] = K.row[s_bit(i)];
    return m;
}

// ---- conflict-free LDS addressing: slot(j) = j ^ mix(j>>6), mix linear 4->6b.
struct Mix { unsigned mk[4]; };
constexpr unsigned mix_apply(Mix m, unsigned h) {
    unsigned r = 0;
    for (int b = 0; b < 4; ++b) if ((h >> b) & 1) r ^= m.mk[b];
    return r;
}
constexpr int rank_of(const unsigned (&v)[6]) {
    unsigned a[6] = {v[0], v[1], v[2], v[3], v[4], v[5]};
    int rank = 0;
    for (int bit = 5; bit >= 0; --bit) {
        int piv = -1;
        for (int i = rank; i < 6; ++i) if ((a[i] >> bit) & 1) { piv = i; break; }
        if (piv < 0) continue;
        unsigned t = a[piv]; a[piv] = a[rank]; a[rank] = t;
        for (int i = 0; i < 6; ++i) if (i != rank && ((a[i] >> bit) & 1)) a[i] ^= a[rank];
        ++rank;
    }
    return rank;
}
constexpr int read_rank(F2Mat M, Mix m) {
    unsigned img[6] = {};
    for (int b = 0; b < 6; ++b) {
        unsigned t = kapply(M, 1u << b);
        img[b] = (t ^ mix_apply(m, t >> 6)) & 63u;
    }
    return rank_of(img);
}
constexpr Mix mix_candidate(int a) {
    Mix m{{0, 0, 0, 0}};
    if (a == 0) return m;
    if (a <= 6) {
        for (int i = 0; i < 4; ++i) m.mk[i] = 1u << ((i + (a - 1)) % 6);
        return m;
    }
    for (int i = 0; i < 4; ++i)
        m.mk[i] = (1u << ((i + (a - 7)) % 6)) | (1u << ((i + (a - 7) + 3) % 6));
    return m;
}
constexpr Mix find_mix(F2Mat M) {
    Mix best{{0, 0, 0, 0}};
    int bestr = read_rank(M, best);
    for (int a = 1; a < 13 && bestr < 6; ++a) {
        Mix c = mix_candidate(a);
        int r = read_rank(M, c);
        if (r > bestr) { best = c; bestr = r; }
    }
    return best;
}
struct RelayTabs { unsigned wb[16]; unsigned rb[16]; unsigned ck[6]; };
constexpr RelayTabs make_relay_m(F2Mat M) {
    Mix mx = find_mix(M);
    RelayTabs t{};
    for (int v = 0; v < 16; ++v) {
        t.wb[v] = ((unsigned)v << 6) ^ mix_apply(mx, (unsigned)v);
        unsigned kv = kapply(M, (unsigned)v << 6);
        t.rb[v] = kv ^ mix_apply(mx, kv >> 6);
    }
    for (int b = 0; b < 6; ++b) {
        unsigned kb = kapply(M, 1u << b);
        t.ck[b] = kb ^ mix_apply(mx, kb >> 6);
    }
    return t;
}
// SEL 0: S (mid-layer swap); SEL 1..5: S*K_{SEL-1} (end of layers 0..4)
constexpr RelayTabs relay_for(int sel) {
    if (sel == 0) return make_relay_m(S_mat());
    return make_relay_m(SK_mat(sel - 1));
}

// runtime K tables for prep
struct DevTabs { unsigned short K[NLAYERS - 1][NQ]; unsigned short K5i[NQ]; };
constexpr DevTabs make_devtabs() {
    DevTabs d{};
    for (int l = 0; l < NLAYERS - 1; ++l) {
        F2Mat K = ring_K(l);
        for (int i = 0; i < NQ; ++i) d.K[l][i] = K.row[i];
    }
    F2Mat K5 = ring_Kinv(NLAYERS - 1);
    for (int i = 0; i < NQ; ++i) d.K5i[i] = K5.row[i];
    return d;
}
__constant__ DevTabs dKT = make_devtabs();
__device__ __forceinline__ unsigned kap_rt(const unsigned short* rows, unsigned j) {
    unsigned r = 0;
#pragma unroll
    for (int i = 0; i < NQ; ++i) r |= (unsigned)(__popc((unsigned)rows[i] & j) & 1) << i;
    return r;
}
__device__ __forceinline__ unsigned s_swap_rt(unsigned j) {
    return (j & 3u) | ((j & 0x3Cu) << 4) | ((j >> 4) & 0x3Cu);
}

// ws layout (floats):
//   [0,120)          {cos(th/2), sin(th/2)} per (l,q)
//   [128, 12416)     6 diagonals, float2[1024] each (head Dpre_0 + 5 boundary)
//   [12416, 13440)   W[m] = wsum[K5inv * S * m]   (layer-5 swap + ring folded)
#define WS_CS   0
#define WS_DIAG 128
#define WS_W    12416

// 24 blocks x 256: part = bid>>2 (0: cs+W+head diag; 1..5: boundary diag l-1)
__global__ __launch_bounds__(256) void prep_kernel(const float* __restrict__ qw,
                                                   const float* __restrict__ fcw,
                                                   float* __restrict__ ws) {
    const int part = blockIdx.x >> 2;
    const int j = (blockIdx.x & 3) * 256 + threadIdx.x;
    float2* D = (float2*)(ws + WS_DIAG);
    if (part == 0) {
        if (j < NLAYERS * NQ) {
            float s, c;
            sincosf(0.5f * qw[3 * j + 1], &s, &c);
            ws[WS_CS + 2 * j]     = c;
            ws[WS_CS + 2 * j + 1] = s;
        }
        {   // readout: fold layer-5 swapped layout (S) and final ring (K5inv)
            unsigned jj = kap_rt(dKT.K5i, s_swap_rt((unsigned)j));
            float w = 0.f;
#pragma unroll
            for (int k = 0; k < NQ; ++k)
                w += fcw[k] * (float)(1 - 2 * (int)((jj >> (NQ - 1 - k)) & 1u));
            ws[WS_W + j] = w;
        }
        {   // head: Dpre_0
            float ang = 0.f;
#pragma unroll
            for (int q = 0; q < NQ; ++q)
                ang += qw[3 * q + 0] * (float)(1 - 2 * (int)((j >> (NQ - 1 - q)) & 1));
            float sn, cn; sincosf(-0.5f * ang, &sn, &cn);
            D[j] = make_float2(cn, sn);
        }
    } else {
        const int l = part - 1;                  // boundary l: Dt_l (canonical)
        unsigned kj = kap_rt(dKT.K[l], (unsigned)j);
        float ang = 0.f;
#pragma unroll
        for (int q = 0; q < NQ; ++q) {
            ang += qw[3 * ((l + 1) * NQ + q) + 0] * (float)(1 - 2 * (int)(((unsigned)j >> (NQ - 1 - q)) & 1u));
            ang += qw[3 * (l * NQ + q) + 2]       * (float)(1 - 2 * (int)((kj >> (NQ - 1 - q)) & 1u));
        }
        float sn, cn; sincosf(-0.5f * ang, &sn, &cn);
        D[(l + 1) * DIM + j] = make_float2(cn, sn);
    }
}

// ---------------- gates (packed f32) ----------------
template<int P>
__device__ __forceinline__ void gate_reg(v2f st[2][16], float c, float s) {
    constexpr int vm = 1 << (P - 6);
#pragma unroll
    for (int v = 0; v < 16; ++v) {
        if (v & vm) continue;
#pragma unroll
        for (int e = 0; e < 2; ++e) {
            v2f a = st[e][v], b = st[e][v | vm];
            st[e][v]      = c * a - s * b;   // v_pk_mul + v_pk_fma
            st[e][v | vm] = s * a + c * b;
        }
    }
}

// lane masks 1,2 via DPP quad_perm (pure VALU)
template<int CTRL>
__device__ __forceinline__ float dpp_x(float x) {
    return __int_as_float(__builtin_amdgcn_update_dpp(__float_as_int(x), __float_as_int(x),
                                                      CTRL, 0xF, 0xF, true));
}
template<int MASK>
__device__ __forceinline__ float lane_xor(float x) {
    if constexpr (MASK == 1) return dpp_x<0xB1>(x);   // quad_perm [1,0,3,2]
    else                     return dpp_x<0x4E>(x);   // quad_perm [2,3,0,1]
}
template<int MASK>
__device__ __forceinline__ void gate_lane(v2f st[2][16], int lane, float c, float s) {
    const float co = (lane & MASK) ? s : -s;   // coeff on partner value
#pragma unroll
    for (int v = 0; v < 16; ++v)
#pragma unroll
        for (int e = 0; e < 2; ++e) {
            v2f a = st[e][v];
            v2f o;
            o.x = lane_xor<MASK>(a.x);
            o.y = lane_xor<MASK>(a.y);
            st[e][v] = c * a + co * o;        // v_pk_mul + v_pk_fma
        }
}

// wave-private LDS permutation: st'[j] = st[M j], M = relay_for(SEL)
template<int SEL>
__device__ __forceinline__ void relayout(v2f st[2][16], int lane, v2f* buf) {
    constexpr RelayTabs RT = relay_for(SEL);
    unsigned rl = 0;
#pragma unroll
    for (int b = 0; b < 6; ++b) rl ^= ((lane >> b) & 1) ? RT.ck[b] : 0u;
#pragma unroll
    for (int e = 0; e < 2; ++e) {
#pragma unroll
        for (int v = 0; v < 16; ++v) buf[RT.wb[v] ^ (unsigned)lane] = st[e][v];
        asm volatile("s_waitcnt lgkmcnt(0)" ::: "memory");
#pragma unroll
        for (int v = 0; v < 16; ++v) st[e][v] = buf[RT.rb[v] ^ rl];
    }
}

// complex diag multiply: r = a.xx*G + a.yy*(-G.y, G.x)
__device__ __forceinline__ void apply_diag(v2f st[2][16], const v2f* __restrict__ g,
                                           int lane) {
#pragma unroll
    for (int v = 0; v < 16; ++v) {
        v2f G = g[(v << 6) | lane];
        v2f nG; nG.x = -G.y; nG.y = G.x;
#pragma unroll
        for (int e = 0; e < 2; ++e) {
            v2f a = st[e][v];
            st[e][v] = a.xx * G + a.yy * nG;
        }
    }
}

template<int L>
__device__ __forceinline__ void do_layer(v2f st[2][16], int lane,
                                         const float* __restrict__ ws, v2f* buf) {
    const float* cs = ws + WS_CS + 2 * (L * NQ);
    gate_reg<9>(st, cs[0], cs[1]);            // q0 (canonical)
    gate_reg<8>(st, cs[2], cs[3]);            // q1
    gate_reg<7>(st, cs[4], cs[5]);            // q2
    gate_reg<6>(st, cs[6], cs[7]);            // q3
    relayout<0>(st, lane, buf);               // S: bits {9..6} <-> {5..2}
    gate_reg<9>(st, cs[8], cs[9]);            // q4 (now reg bit 9)
    gate_reg<8>(st, cs[10], cs[11]);          // q5
    gate_reg<7>(st, cs[12], cs[13]);          // q6
    gate_reg<6>(st, cs[14], cs[15]);          // q7
    gate_lane<2>(st, lane, cs[16], cs[17]);   // q8 (bit 1, S-invariant)
    gate_lane<1>(st, lane, cs[18], cs[19]);   // q9 (bit 0)
    if constexpr (L < NLAYERS - 1) {
        relayout<L + 1>(st, lane, buf);       // S*K_L: unswap + ring in one
        apply_diag(st, (const v2f*)(ws + WS_DIAG) + (L + 1) * DIM, lane);
    }
    // L==5: stay swapped; W folds S and ring5
}

__global__ __launch_bounds__(256, 4) void qsim_kernel(const float* __restrict__ x,
                                                      const float* __restrict__ ws,
                                                      const float* __restrict__ fcb,
                                                      float* __restrict__ out) {
    __shared__ v2f lbuf[4][DIM];
    const int lane = threadIdx.x & 63;
    const int wid  = threadIdx.x >> 6;
    const int b0   = blockIdx.x * 8 + wid * 2;
    v2f* buf = lbuf[wid];

    v2f st[2][16];
#pragma unroll
    for (int e = 0; e < 2; ++e) {
        float cq[NQ], sq[NQ];
#pragma unroll
        for (int q = 0; q < NQ; ++q) {
            float ss, cc;
            __sincosf(0.5f * x[(b0 + e) * NQ + q], &ss, &cc);
            sq[q] = ss; cq[q] = cc;
        }
#pragma unroll
        for (int v = 0; v < 16; ++v) {
            const int i = (v << 6) | lane;
            float mag = 1.f;
#pragma unroll
            for (int q = 0; q < NQ; ++q) {
                int bit = (i >> (NQ - 1 - q)) & 1;
                mag *= bit ? sq[q] : cq[q];
            }
            const int k = __popc(i) & 3;
            float re = (k == 0) ? mag : ((k == 2) ? -mag : 0.f);
            float im = (k == 1) ? -mag : ((k == 3) ? mag : 0.f);
            v2f a; a.x = re; a.y = im;
            st[e][v] = a;
        }
    }

    apply_diag(st, (const v2f*)(ws + WS_DIAG), lane);      // Dpre_0
    do_layer<0>(st, lane, ws, buf);
    do_layer<1>(st, lane, ws, buf);
    do_layer<2>(st, lane, ws, buf);
    do_layer<3>(st, lane, ws, buf);
    do_layer<4>(st, lane, ws, buf);
    do_layer<5>(st, lane, ws, buf);

    const float* W = ws + WS_W;
    float acc0 = 0.f, acc1 = 0.f;
#pragma unroll
    for (int v = 0; v < 16; ++v) {
        float w = W[(v << 6) | lane];
        float p0 = st[0][v].x * st[0][v].x + st[0][v].y * st[0][v].y;
        float p1 = st[1][v].x * st[1][v].x + st[1][v].y * st[1][v].y;
        acc0 = fmaf(p0, w, acc0);
        acc1 = fmaf(p1, w, acc1);
    }
#pragma unroll
    for (int off = 32; off > 0; off >>= 1) {
        acc0 += __shfl_down(acc0, off, 64);
        acc1 += __shfl_down(acc1, off, 64);
    }
    if (lane == 0) {
        float bias = fcb[0];
        out[b0]     = acc0 + bias;
        out[b0 + 1] = acc1 + bias;
    }
}

extern "C" void kernel_launch(void* const* d_in, const int* in_sizes, int n_in,
                              void* d_out, int out_size, void* d_ws, size_t ws_size,
                              hipStream_t stream) {
    const float* x   = (const float*)d_in[0];
    const float* qw  = (const float*)d_in[1];
    const float* fcw = (const float*)d_in[2];
    const float* fcb = (const float*)d_in[3];
    float* out = (float*)d_out;
    float* ws  = (float*)d_ws;

    prep_kernel<<<24, 256, 0, stream>>>(qw, fcw, ws);
    qsim_kernel<<<BATCH / 8, 256, 0, stream>>>(x, ws, fcb, out);
}

// Round 16
// 175.432 us; speedup vs baseline: 11.9636x; 1.0458x over previous
//
#include <hip/hip_runtime.h>
#include <math.h>

#define NQ 10
#define DIM 1024
#define NLAYERS 6
#define BATCH 16384

typedef float v2f __attribute__((ext_vector_type(2)));

// forced packed-fp32 ops (full-rate on CDNA: one instr = 2 FMA/lane)
__device__ __forceinline__ v2f pk_mul(v2f a, v2f b) {
    v2f d; asm("v_pk_mul_f32 %0, %1, %2" : "=v"(d) : "v"(a), "v"(b)); return d;
}
__device__ __forceinline__ v2f pk_fma(v2f a, v2f b, v2f c) {
    v2f d; asm("v_pk_fma_f32 %0, %1, %2, %3" : "=v"(d) : "v"(a), "v"(b), "v"(c)); return d;
}
__device__ __forceinline__ v2f bcast2(float x) { v2f r; r.x = x; r.y = x; return r; }

// ============================================================================
// Per layer: q0-q3 reg gates -> S-relayout (swap storage bits 9..6 <-> 5..2)
// -> q4-q7 reg gates -> q8,q9 DPP lane gates -> relayout M = S*K_l (restores
// canonical layout AND applies the CNOT ring) -> boundary diagonal.
// Layer 5: no trailing relayout; readout folds S and ring5 into W.
// Rot = D1*Y*D2; diagonals collapse into per-layer diagonals (precomputed).
// All updates are complex-value x real-shared-scalar -> forced v_pk_*_f32.
// ============================================================================
struct F2Mat { unsigned short row[NQ]; };

constexpr F2Mat f2_id() {
    F2Mat m{}; for (int i = 0; i < NQ; ++i) m.row[i] = (unsigned short)(1u << i);
    return m;
}
constexpr F2Mat f2_mul(F2Mat A, F2Mat B) {
    F2Mat C{};
    for (int i = 0; i < NQ; ++i) {
        unsigned r = 0;
        for (int j = 0; j < NQ; ++j) if ((A.row[i] >> j) & 1u) r ^= B.row[j];
        C.row[i] = (unsigned short)r;
    }
    return C;
}
constexpr F2Mat L_mat(int pc, int pt) {
    F2Mat m = f2_id();
    m.row[pt] = (unsigned short)((1u << pt) | (1u << pc));
    return m;
}
constexpr F2Mat ring_K(int l) {      // psi'[i] = psi[K i]
    int r = l % (NQ - 1) + 1;
    F2Mat K = f2_id();
    for (int w = 0; w < NQ; ++w) K = f2_mul(K, L_mat(NQ - 1 - w, NQ - 1 - (w + r) % NQ));
    return K;
}
constexpr F2Mat ring_Kinv(int l) {
    int r = l % (NQ - 1) + 1;
    F2Mat K = f2_id();
    for (int w = NQ - 1; w >= 0; --w) K = f2_mul(K, L_mat(NQ - 1 - w, NQ - 1 - (w + r) % NQ));
    return K;
}
constexpr unsigned kapply(F2Mat K, unsigned j) {
    unsigned r = 0;
    for (int i = 0; i < NQ; ++i) r |= (unsigned)(__builtin_popcount(K.row[i] & j) & 1) << i;
    return r;
}

// bit-swap permutation S: exchange bit positions {9,8,7,6} <-> {5,4,3,2}
constexpr int s_bit(int i) { return (i >= 2 && i <= 5) ? i + 4 : (i >= 6 && i <= 9) ? i - 4 : i; }
constexpr F2Mat S_mat() {
    F2Mat m{};
    for (int i = 0; i < NQ; ++i) m.row[i] = (unsigned short)(1u << s_bit(i));
    return m;
}
// M = S*K_l  (j -> S(K j)); bit i of S(x) = bit s(i) of x
constexpr F2Mat SK_mat(int l) {
    F2Mat K = ring_K(l);
    F2Mat m{};
    for (int i = 0; i < NQ; ++i) m.row[i] = K.row[s_bit(i)];
    return m;
}

// ---- conflict-free LDS addressing: slot(j) = j ^ mix(j>>6), mix linear 4->6b.
struct Mix { unsigned mk[4]; };
constexpr unsigned mix_apply(Mix m, unsigned h) {
    unsigned r = 0;
    for (int b = 0; b < 4; ++b) if ((h >> b) & 1) r ^= m.mk[b];
    return r;
}
constexpr int rank_of(const unsigned (&v)[6]) {
    unsigned a[6] = {v[0], v[1], v[2], v[3], v[4], v[5]};
    int rank = 0;
    for (int bit = 5; bit >= 0; --bit) {
        int piv = -1;
        for (int i = rank; i < 6; ++i) if ((a[i] >> bit) & 1) { piv = i; break; }
        if (piv < 0) continue;
        unsigned t = a[piv]; a[piv] = a[rank]; a[rank] = t;
        for (int i = 0; i < 6; ++i) if (i != rank && ((a[i] >> bit) & 1)) a[i] ^= a[rank];
        ++rank;
    }
    return rank;
}
constexpr int read_rank(F2Mat M, Mix m) {
    unsigned img[6] = {};
    for (int b = 0; b < 6; ++b) {
        unsigned t = kapply(M, 1u << b);
        img[b] = (t ^ mix_apply(m, t >> 6)) & 63u;
    }
    return rank_of(img);
}
constexpr Mix mix_candidate(int a) {
    Mix m{{0, 0, 0, 0}};
    if (a == 0) return m;
    if (a <= 6) {
        for (int i = 0; i < 4; ++i) m.mk[i] = 1u << ((i + (a - 1)) % 6);
        return m;
    }
    for (int i = 0; i < 4; ++i)
        m.mk[i] = (1u << ((i + (a - 7)) % 6)) | (1u << ((i + (a - 7) + 3) % 6));
    return m;
}
constexpr Mix find_mix(F2Mat M) {
    Mix best{{0, 0, 0, 0}};
    int bestr = read_rank(M, best);
    for (int a = 1; a < 13 && bestr < 6; ++a) {
        Mix c = mix_candidate(a);
        int r = read_rank(M, c);
        if (r > bestr) { best = c; bestr = r; }
    }
    return best;
}
struct RelayTabs { unsigned wb[16]; unsigned rb[16]; unsigned ck[6]; };
constexpr RelayTabs make_relay_m(F2Mat M) {
    Mix mx = find_mix(M);
    RelayTabs t{};
    for (int v = 0; v < 16; ++v) {
        t.wb[v] = ((unsigned)v << 6) ^ mix_apply(mx, (unsigned)v);
        unsigned kv = kapply(M, (unsigned)v << 6);
        t.rb[v] = kv ^ mix_apply(mx, kv >> 6);
    }
    for (int b = 0; b < 6; ++b) {
        unsigned kb = kapply(M, 1u << b);
        t.ck[b] = kb ^ mix_apply(mx, kb >> 6);
    }
    return t;
}
// SEL 0: S (mid-layer swap); SEL 1..5: S*K_{SEL-1} (end of layers 0..4)
constexpr RelayTabs relay_for(int sel) {
    if (sel == 0) return make_relay_m(S_mat());
    return make_relay_m(SK_mat(sel - 1));
}

// runtime K tables for prep
struct DevTabs { unsigned short K[NLAYERS - 1][NQ]; unsigned short K5i[NQ]; };
constexpr DevTabs make_devtabs() {
    DevTabs d{};
    for (int l = 0; l < NLAYERS - 1; ++l) {
        F2Mat K = ring_K(l);
        for (int i = 0; i < NQ; ++i) d.K[l][i] = K.row[i];
    }
    F2Mat K5 = ring_Kinv(NLAYERS - 1);
    for (int i = 0; i < NQ; ++i) d.K5i[i] = K5.row[i];
    return d;
}
__constant__ DevTabs dKT = make_devtabs();
__device__ __forceinline__ unsigned kap_rt(const unsigned short* rows, unsigned j) {
    unsigned r = 0;
#pragma unroll
    for (int i = 0; i < NQ; ++i) r |= (unsigned)(__popc((unsigned)rows[i] & j) & 1) << i;
    return r;
}
__device__ __forceinline__ unsigned s_swap_rt(unsigned j) {
    return (j & 3u) | ((j & 0x3Cu) << 4) | ((j >> 4) & 0x3Cu);
}

// ws layout (floats):
//   [0,120)          {cos(th/2), sin(th/2)} per (l,q)
//   [128, 12416)     6 diagonals, float2[1024] each (head Dpre_0 + 5 boundary)
//   [12416, 13440)   W[m] = wsum[K5inv * S * m]   (layer-5 swap + ring folded)
#define WS_CS   0
#define WS_DIAG 128
#define WS_W    12416

// 24 blocks x 256: part = bid>>2 (0: cs+W+head diag; 1..5: boundary diag l-1)
__global__ __launch_bounds__(256) void prep_kernel(const float* __restrict__ qw,
                                                   const float* __restrict__ fcw,
                                                   float* __restrict__ ws) {
    const int part = blockIdx.x >> 2;
    const int j = (blockIdx.x & 3) * 256 + threadIdx.x;
    float2* D = (float2*)(ws + WS_DIAG);
    if (part == 0) {
        if (j < NLAYERS * NQ) {
            float s, c;
            sincosf(0.5f * qw[3 * j + 1], &s, &c);
            ws[WS_CS + 2 * j]     = c;
            ws[WS_CS + 2 * j + 1] = s;
        }
        {   // readout: fold layer-5 swapped layout (S) and final ring (K5inv)
            unsigned jj = kap_rt(dKT.K5i, s_swap_rt((unsigned)j));
            float w = 0.f;
#pragma unroll
            for (int k = 0; k < NQ; ++k)
                w += fcw[k] * (float)(1 - 2 * (int)((jj >> (NQ - 1 - k)) & 1u));
            ws[WS_W + j] = w;
        }
        {   // head: Dpre_0
            float ang = 0.f;
#pragma unroll
            for (int q = 0; q < NQ; ++q)
                ang += qw[3 * q + 0] * (float)(1 - 2 * (int)((j >> (NQ - 1 - q)) & 1));
            float sn, cn; sincosf(-0.5f * ang, &sn, &cn);
            D[j] = make_float2(cn, sn);
        }
    } else {
        const int l = part - 1;                  // boundary l: Dt_l (canonical)
        unsigned kj = kap_rt(dKT.K[l], (unsigned)j);
        float ang = 0.f;
#pragma unroll
        for (int q = 0; q < NQ; ++q) {
            ang += qw[3 * ((l + 1) * NQ + q) + 0] * (float)(1 - 2 * (int)(((unsigned)j >> (NQ - 1 - q)) & 1u));
            ang += qw[3 * (l * NQ + q) + 2]       * (float)(1 - 2 * (int)((kj >> (NQ - 1 - q)) & 1u));
        }
        float sn, cn; sincosf(-0.5f * ang, &sn, &cn);
        D[(l + 1) * DIM + j] = make_float2(cn, sn);
    }
}

// ---------------- gates (forced v_pk math) ----------------
template<int P>
__device__ __forceinline__ void gate_reg(v2f st[2][16], float c, float s) {
    constexpr int vm = 1 << (P - 6);
    const v2f cc = bcast2(c), ss = bcast2(s), nss = bcast2(-s);
#pragma unroll
    for (int v = 0; v < 16; ++v) {
        if (v & vm) continue;
#pragma unroll
        for (int e = 0; e < 2; ++e) {
            v2f a = st[e][v], b = st[e][v | vm];
            st[e][v]      = pk_fma(nss, b, pk_mul(cc, a));  // c*a - s*b
            st[e][v | vm] = pk_fma(cc, b, pk_mul(ss, a));   // s*a + c*b
        }
    }
}

// lane masks 1,2 via DPP quad_perm (pure VALU)
template<int CTRL>
__device__ __forceinline__ float dpp_x(float x) {
    return __int_as_float(__builtin_amdgcn_update_dpp(__float_as_int(x), __float_as_int(x),
                                                      CTRL, 0xF, 0xF, true));
}
template<int MASK>
__device__ __forceinline__ float lane_xor(float x) {
    if constexpr (MASK == 1) return dpp_x<0xB1>(x);   // quad_perm [1,0,3,2]
    else                     return dpp_x<0x4E>(x);   // quad_perm [2,3,0,1]
}
template<int MASK>
__device__ __forceinline__ void gate_lane(v2f st[2][16], int lane, float c, float s) {
    const float co = (lane & MASK) ? s : -s;   // coeff on partner value
    const v2f cc = bcast2(c), coo = bcast2(co);
#pragma unroll
    for (int v = 0; v < 16; ++v)
#pragma unroll
        for (int e = 0; e < 2; ++e) {
            v2f a = st[e][v];
            v2f o;
            o.x = lane_xor<MASK>(a.x);
            o.y = lane_xor<MASK>(a.y);
            st[e][v] = pk_fma(coo, o, pk_mul(cc, a));   // c*a + co*o
        }
}

// wave-private LDS permutation: st'[j] = st[M j], M = relay_for(SEL)
template<int SEL>
__device__ __forceinline__ void relayout(v2f st[2][16], int lane, v2f* buf) {
    constexpr RelayTabs RT = relay_for(SEL);
    unsigned rl = 0;
#pragma unroll
    for (int b = 0; b < 6; ++b) rl ^= ((lane >> b) & 1) ? RT.ck[b] : 0u;
#pragma unroll
    for (int e = 0; e < 2; ++e) {
#pragma unroll
        for (int v = 0; v < 16; ++v) buf[RT.wb[v] ^ (unsigned)lane] = st[e][v];
        asm volatile("s_waitcnt lgkmcnt(0)" ::: "memory");
#pragma unroll
        for (int v = 0; v < 16; ++v) st[e][v] = buf[RT.rb[v] ^ rl];
    }
}

// complex diag: st' = G.xx*a + G.yy*rot(a), rot(a) = (-a.y, a.x)
__device__ __forceinline__ void apply_diag(v2f st[2][16], const v2f* __restrict__ g,
                                           int lane) {
#pragma unroll
    for (int v = 0; v < 16; ++v) {
        v2f G = g[(v << 6) | lane];
        const v2f Gxx = bcast2(G.x), Gyy = bcast2(G.y);   // shared by both streams
#pragma unroll
        for (int e = 0; e < 2; ++e) {
            v2f a = st[e][v];
            v2f ra; ra.x = -a.y; ra.y = a.x;
            st[e][v] = pk_fma(Gyy, ra, pk_mul(Gxx, a));
        }
    }
}

template<int L>
__device__ __forceinline__ void do_layer(v2f st[2][16], int lane,
                                         const float* __restrict__ ws, v2f* buf) {
    const float* cs = ws + WS_CS + 2 * (L * NQ);
    gate_reg<9>(st, cs[0], cs[1]);            // q0 (canonical)
    gate_reg<8>(st, cs[2], cs[3]);            // q1
    gate_reg<7>(st, cs[4], cs[5]);            // q2
    gate_reg<6>(st, cs[6], cs[7]);            // q3
    relayout<0>(st, lane, buf);               // S: bits {9..6} <-> {5..2}
    gate_reg<9>(st, cs[8], cs[9]);            // q4 (now reg bit 9)
    gate_reg<8>(st, cs[10], cs[11]);          // q5
    gate_reg<7>(st, cs[12], cs[13]);          // q6
    gate_reg<6>(st, cs[14], cs[15]);          // q7
    gate_lane<2>(st, lane, cs[16], cs[17]);   // q8 (bit 1, S-invariant)
    gate_lane<1>(st, lane, cs[18], cs[19]);   // q9 (bit 0)
    if constexpr (L < NLAYERS - 1) {
        relayout<L + 1>(st, lane, buf);       // S*K_L: unswap + ring in one
        apply_diag(st, (const v2f*)(ws + WS_DIAG) + (L + 1) * DIM, lane);
    }
    // L==5: stay swapped; W folds S and ring5
}

__global__ __launch_bounds__(256, 4) void qsim_kernel(const float* __restrict__ x,
                                                      const float* __restrict__ ws,
                                                      const float* __restrict__ fcb,
                                                      float* __restrict__ out) {
    __shared__ v2f lbuf[4][DIM];
    const int lane = threadIdx.x & 63;
    const int wid  = threadIdx.x >> 6;
    const int b0   = blockIdx.x * 8 + wid * 2;
    v2f* buf = lbuf[wid];

    v2f st[2][16];
#pragma unroll
    for (int e = 0; e < 2; ++e) {
        float cq[NQ], sq[NQ];
#pragma unroll
        for (int q = 0; q < NQ; ++q) {
            float ss, cc;
            __sincosf(0.5f * x[(b0 + e) * NQ + q], &ss, &cc);
            sq[q] = ss; cq[q] = cc;
        }
#pragma unroll
        for (int v = 0; v < 16; ++v) {
            const int i = (v << 6) | lane;
            float mag = 1.f;
#pragma unroll
            for (int q = 0; q < NQ; ++q) {
                int bit = (i >> (NQ - 1 - q)) & 1;
                mag *= bit ? sq[q] : cq[q];
            }
            const int k = __popc(i) & 3;
            float re = (k == 0) ? mag : ((k == 2) ? -mag : 0.f);
            float im = (k == 1) ? -mag : ((k == 3) ? mag : 0.f);
            v2f a; a.x = re; a.y = im;
            st[e][v] = a;
        }
    }

    apply_diag(st, (const v2f*)(ws + WS_DIAG), lane);      // Dpre_0
    do_layer<0>(st, lane, ws, buf);
    do_layer<1>(st, lane, ws, buf);
    do_layer<2>(st, lane, ws, buf);
    do_layer<3>(st, lane, ws, buf);
    do_layer<4>(st, lane, ws, buf);
    do_layer<5>(st, lane, ws, buf);

    const float* W = ws + WS_W;
    float acc0 = 0.f, acc1 = 0.f;
#pragma unroll
    for (int v = 0; v < 16; ++v) {
        float w = W[(v << 6) | lane];
        float p0 = st[0][v].x * st[0][v].x + st[0][v].y * st[0][v].y;
        float p1 = st[1][v].x * st[1][v].x + st[1][v].y * st[1][v].y;
        acc0 = fmaf(p0, w, acc0);
        acc1 = fmaf(p1, w, acc1);
    }
#pragma unroll
    for (int off = 32; off > 0; off >>= 1) {
        acc0 += __shfl_down(acc0, off, 64);
        acc1 += __shfl_down(acc1, off, 64);
    }
    if (lane == 0) {
        float bias = fcb[0];
        out[b0]     = acc0 + bias;
        out[b0 + 1] = acc1 + bias;
    }
}

extern "C" void kernel_launch(void* const* d_in, const int* in_sizes, int n_in,
                              void* d_out, int out_size, void* d_ws, size_t ws_size,
                              hipStream_t stream) {
    const float* x   = (const float*)d_in[0];
    const float* qw  = (const float*)d_in[1];
    const float* fcw = (const float*)d_in[2];
    const float* fcb = (const float*)d_in[3];
    float* out = (float*)d_out;
    float* ws  = (float*)d_ws;

    prep_kernel<<<24, 256, 0, stream>>>(qw, fcw, ws);
    qsim_kernel<<<BATCH / 8, 256, 0, stream>>>(x, ws, fcb, out);
}